// Round 1
// baseline (470.603 us; speedup 1.0000x reference)
//
#include <hip/hip_runtime.h>
#include <cmath>

#define LOG2E 1.4426950408889634f

typedef __attribute__((ext_vector_type(8))) short bf16x8;
typedef __attribute__((ext_vector_type(8))) _Float16 half8;
typedef __attribute__((ext_vector_type(4))) float f32x4;

__device__ inline unsigned short bf16_rne(float f) {
    unsigned u = __builtin_bit_cast(unsigned, f);
    u += 0x7fff + ((u >> 16) & 1);
    return (unsigned short)(u >> 16);
}

// ---------------------------------------------------------------------------
// Projection GEMM: C[row, col] = sum_f A[row,f] * W[f,col], K = 1024 fixed.
// mode 0 = Q: writes qu bf16 [B,T,NH] (=acc+u_bias) and qv fp16 [B,T,NH] (=acc+v_bias)
// mode 1 = K: writes bf16 [B,S,NH]
// mode 2 = V: writes bf16 transposed [B,N,H,S]
// mode 3 = R: writes fp16 [N,M,H] (rows guarded to 2049)
// ---------------------------------------------------------------------------
__global__ __launch_bounds__(256) void proj_kernel(
    const float* __restrict__ A, const float* __restrict__ W,
    int nrows, int mode,
    unsigned short* __restrict__ o_b16, _Float16* __restrict__ o_f16,
    const float* __restrict__ ub, const float* __restrict__ vb)
{
    __shared__ _Float16 As[64][56];   // stride 56 fp16: 2-way bank alias only (free)
    __shared__ _Float16 Ws[64][56];   // Ws[col][k]
    const int tid = threadIdx.x;
    const int lane = tid & 63, w = tid >> 6, c = lane & 15, g = lane >> 4;
    const int row0 = blockIdx.x * 64, col0 = blockIdx.y * 64;

    f32x4 acc[4] = {};
    const int ar = tid >> 2, akc = (tid & 3) * 8;   // A staging: row ar, k chunk
    const int wc = tid & 63, wk = (tid >> 6) * 8;   // W staging: col wc, k chunk
    const bool a_ok = (row0 + ar) < nrows;
    const float* Aptr = A + (size_t)(row0 + ar) * 1024 + akc;
    const float* Wptr = W + (size_t)wk * 1024 + col0 + wc;

    for (int k0 = 0; k0 < 1024; k0 += 32) {
        half8 ah;
        if (a_ok) {
            float4 t0 = *(const float4*)(Aptr + k0);
            float4 t1 = *(const float4*)(Aptr + k0 + 4);
            ah[0]=(_Float16)t0.x; ah[1]=(_Float16)t0.y; ah[2]=(_Float16)t0.z; ah[3]=(_Float16)t0.w;
            ah[4]=(_Float16)t1.x; ah[5]=(_Float16)t1.y; ah[6]=(_Float16)t1.z; ah[7]=(_Float16)t1.w;
        } else {
            for (int i = 0; i < 8; i++) ah[i] = (_Float16)0.f;
        }
        *(half8*)&As[ar][akc] = ah;
        half8 wh;
        #pragma unroll
        for (int i = 0; i < 8; i++) wh[i] = (_Float16)Wptr[(size_t)(k0 + i) * 1024];
        *(half8*)&Ws[wc][wk] = wh;
        __syncthreads();
        half8 af = *(const half8*)&As[16 * w + c][g * 8];
        #pragma unroll
        for (int j = 0; j < 4; j++) {
            half8 bf = *(const half8*)&Ws[16 * j + c][g * 8];
            acc[j] = __builtin_amdgcn_mfma_f32_16x16x32_f16(af, bf, acc[j], 0, 0, 0);
        }
        __syncthreads();
    }

    #pragma unroll
    for (int j = 0; j < 4; j++) {
        #pragma unroll
        for (int rg = 0; rg < 4; rg++) {
            int r_g = row0 + 16 * w + g * 4 + rg;
            int cg  = col0 + 16 * j + c;
            float v = acc[j][rg];
            if (mode == 0) {
                size_t o = (size_t)r_g * 1024 + cg;
                o_b16[o] = bf16_rne(v + ub[cg]);
                o_f16[o] = (_Float16)(v + vb[cg]);
            } else if (mode == 1) {
                o_b16[(size_t)r_g * 1024 + cg] = bf16_rne(v);
            } else if (mode == 2) {
                int b = r_g >> 11, s = r_g & 2047;
                o_b16[((size_t)(b * 16 + (cg >> 6)) * 64 + (cg & 63)) * 2048 + s] = bf16_rne(v);
            } else {
                if (r_g < nrows)
                    o_f16[((size_t)(cg >> 6) * 2049 + r_g) * 64 + (cg & 63)] = (_Float16)v;
            }
        }
    }
}

// ---------------------------------------------------------------------------
// BD GEMM + shifted scatter: bd[t][m'] = sum_h qv[b,t,n,h]*r[m',n,h]
// main:    s1 = m' + t - 1023 in [0,2048)  -> BDs[t][s1]
// garbage: s2 = m' + t + 1026 < 2048, t>=1 -> BDs[t-1][s2]   (mutually exclusive)
// zero diagonal BDs[t][t+1026] written by m-tile 0 blocks.
// ---------------------------------------------------------------------------
__global__ __launch_bounds__(256) void bd_kernel(
    const _Float16* __restrict__ qv, const _Float16* __restrict__ r,
    _Float16* __restrict__ bds)
{
    const int tid = threadIdx.x;
    const int lane = tid & 63, w = tid >> 6, c = lane & 15, g = lane >> 4;
    const int m0 = blockIdx.x * 64, t0 = blockIdx.y * 64 + 16 * w;
    const int bn = blockIdx.z, b = bn >> 4, n = bn & 15;

    const _Float16* qp = qv + (size_t)(b * 1024 + t0 + c) * 1024 + n * 64 + g * 8;
    half8 a0 = *(const half8*)qp;
    half8 a1 = *(const half8*)(qp + 32);

    f32x4 acc[4];
    #pragma unroll
    for (int j = 0; j < 4; j++) {
        int m = m0 + 16 * j + c;
        int mc = m > 2048 ? 2048 : m;
        const _Float16* rp = r + ((size_t)n * 2049 + mc) * 64 + g * 8;
        half8 b0 = *(const half8*)rp;
        half8 b1 = *(const half8*)(rp + 32);
        f32x4 z = {};
        z = __builtin_amdgcn_mfma_f32_16x16x32_f16(a0, b0, z, 0, 0, 0);
        z = __builtin_amdgcn_mfma_f32_16x16x32_f16(a1, b1, z, 0, 0, 0);
        acc[j] = z;
    }
    #pragma unroll
    for (int j = 0; j < 4; j++) {
        int m = m0 + 16 * j + c;
        if (m > 2048) continue;
        #pragma unroll
        for (int rg = 0; rg < 4; rg++) {
            int t = t0 + g * 4 + rg;
            _Float16 val = (_Float16)acc[j][rg];
            int s1 = m + t - 1023;
            if ((unsigned)s1 < 2048u) {
                bds[((size_t)(bn << 10) + t) * 2048 + s1] = val;
            } else {
                int s2 = m + t + 1026;
                if (t >= 1 && s2 < 2048)
                    bds[((size_t)(bn << 10) + t - 1) * 2048 + s2] = val;
            }
        }
    }
    if (blockIdx.x == 0 && tid < 64) {
        int t = blockIdx.y * 64 + tid;
        if (t + 1026 < 2048)
            bds[((size_t)(bn << 10) + t) * 2048 + t + 1026] = (_Float16)0.f;
    }
}

// ---------------------------------------------------------------------------
// Flash attention: grid (T/64, B*N). 64 q-rows per block, 64-wide s-tiles,
// bf16 16x16x32 MFMA, online softmax, bias from pre-shifted BDs.
// ---------------------------------------------------------------------------
__global__ __launch_bounds__(256) void flash_kernel(
    const unsigned short* __restrict__ qu, const unsigned short* __restrict__ kg,
    const unsigned short* __restrict__ vt, const _Float16* __restrict__ bds,
    _Float16* __restrict__ attn)
{
    __shared__ unsigned short Ks[64][72];
    __shared__ unsigned short Vs[64][72];
    __shared__ unsigned short Ps[64][72];
    const int tid = threadIdx.x;
    const int lane = tid & 63, w = tid >> 6, c = lane & 15, g = lane >> 4;
    const int t0 = blockIdx.x * 64;
    const int bn = blockIdx.y, b = bn >> 4, n = bn & 15;

    const unsigned short* qp = qu + (size_t)(b * 1024 + t0 + 16 * w + c) * 1024 + n * 64 + g * 8;
    bf16x8 qf0 = *(const bf16x8*)qp;
    bf16x8 qf1 = *(const bf16x8*)(qp + 32);

    f32x4 o[4] = {};
    float m_i[4], l_i[4];
    #pragma unroll
    for (int rg = 0; rg < 4; rg++) { m_i[rg] = -INFINITY; l_i[rg] = 0.f; }

    const _Float16* bdrow[4];
    #pragma unroll
    for (int rg = 0; rg < 4; rg++)
        bdrow[rg] = bds + ((size_t)bn * 1024 + t0 + 16 * w + g * 4 + rg) * 2048;

    const int sr = tid >> 2, scc = (tid & 3) * 16;
    const unsigned short* kstage = kg + (size_t)(b * 2048 + sr) * 1024 + n * 64 + scc;
    const unsigned short* vstage = vt + ((size_t)bn * 64 + sr) * 2048 + scc;

    for (int s0 = 0; s0 < 2048; s0 += 64) {
        *(uint4*)&Ks[sr][scc]     = *(const uint4*)(kstage + (size_t)s0 * 1024);
        *(uint4*)&Ks[sr][scc + 8] = *(const uint4*)(kstage + (size_t)s0 * 1024 + 8);
        *(uint4*)&Vs[sr][scc]     = *(const uint4*)(vstage + s0);
        *(uint4*)&Vs[sr][scc + 8] = *(const uint4*)(vstage + s0 + 8);
        __syncthreads();

        float lg[4][4];
        #pragma unroll
        for (int j = 0; j < 4; j++) {
            bf16x8 kf0 = *(const bf16x8*)&Ks[16 * j + c][g * 8];
            bf16x8 kf1 = *(const bf16x8*)&Ks[16 * j + c][32 + g * 8];
            f32x4 sa = {};
            sa = __builtin_amdgcn_mfma_f32_16x16x32_bf16(qf0, kf0, sa, 0, 0, 0);
            sa = __builtin_amdgcn_mfma_f32_16x16x32_bf16(qf1, kf1, sa, 0, 0, 0);
            #pragma unroll
            for (int rg = 0; rg < 4; rg++) {
                float bd = (float)bdrow[rg][s0 + 16 * j + c];
                lg[j][rg] = (sa[rg] + bd) * 0.125f;
            }
        }

        float nm[4], al[4], rs[4];
        #pragma unroll
        for (int rg = 0; rg < 4; rg++) {
            float m2 = fmaxf(fmaxf(lg[0][rg], lg[1][rg]), fmaxf(lg[2][rg], lg[3][rg]));
            #pragma unroll
            for (int off = 1; off < 16; off <<= 1)
                m2 = fmaxf(m2, __shfl_xor(m2, off, 16));
            nm[rg] = fmaxf(m_i[rg], m2);
            al[rg] = exp2f((m_i[rg] - nm[rg]) * LOG2E);
            rs[rg] = 0.f;
        }
        #pragma unroll
        for (int j = 0; j < 4; j++) {
            #pragma unroll
            for (int rg = 0; rg < 4; rg++) {
                float p = exp2f((lg[j][rg] - nm[rg]) * LOG2E);
                rs[rg] += p;
                Ps[16 * w + g * 4 + rg][16 * j + c] = bf16_rne(p);
            }
        }
        #pragma unroll
        for (int rg = 0; rg < 4; rg++) {
            float s2 = rs[rg];
            #pragma unroll
            for (int off = 1; off < 16; off <<= 1)
                s2 += __shfl_xor(s2, off, 16);
            l_i[rg] = l_i[rg] * al[rg] + s2;
            m_i[rg] = nm[rg];
        }
        #pragma unroll
        for (int j = 0; j < 4; j++)
            #pragma unroll
            for (int rg = 0; rg < 4; rg++)
                o[j][rg] *= al[rg];

        bf16x8 pf0 = *(const bf16x8*)&Ps[16 * w + c][g * 8];
        bf16x8 pf1 = *(const bf16x8*)&Ps[16 * w + c][32 + g * 8];
        #pragma unroll
        for (int j = 0; j < 4; j++) {
            bf16x8 vf0 = *(const bf16x8*)&Vs[16 * j + c][g * 8];
            bf16x8 vf1 = *(const bf16x8*)&Vs[16 * j + c][32 + g * 8];
            o[j] = __builtin_amdgcn_mfma_f32_16x16x32_bf16(pf0, vf0, o[j], 0, 0, 0);
            o[j] = __builtin_amdgcn_mfma_f32_16x16x32_bf16(pf1, vf1, o[j], 0, 0, 0);
        }
        __syncthreads();
    }

    #pragma unroll
    for (int j = 0; j < 4; j++) {
        #pragma unroll
        for (int rg = 0; rg < 4; rg++) {
            int t = t0 + 16 * w + g * 4 + rg;
            float val = o[j][rg] / l_i[rg];
            attn[(size_t)(b * 1024 + t) * 1024 + n * 64 + 16 * j + c] = (_Float16)val;
        }
    }
}

// ---------------------------------------------------------------------------
// Output GEMM: out[bt,f] = sum_nh attn[bt,nh]*Wout[nh,f] + b_out[f]
// ---------------------------------------------------------------------------
__global__ __launch_bounds__(256) void out_kernel(
    const _Float16* __restrict__ A, const float* __restrict__ W,
    const float* __restrict__ bias, float* __restrict__ out)
{
    __shared__ _Float16 As[64][56];
    __shared__ _Float16 Ws[64][56];
    const int tid = threadIdx.x;
    const int lane = tid & 63, w = tid >> 6, c = lane & 15, g = lane >> 4;
    const int row0 = blockIdx.x * 64, col0 = blockIdx.y * 64;
    f32x4 acc[4] = {};
    const int ar = tid >> 2, akc = (tid & 3) * 8;
    const int wc = tid & 63, wk = (tid >> 6) * 8;
    const _Float16* Aptr = A + (size_t)(row0 + ar) * 1024 + akc;
    const float* Wptr = W + (size_t)wk * 1024 + col0 + wc;
    for (int k0 = 0; k0 < 1024; k0 += 32) {
        *(half8*)&As[ar][akc] = *(const half8*)(Aptr + k0);
        half8 wh;
        #pragma unroll
        for (int i = 0; i < 8; i++) wh[i] = (_Float16)Wptr[(size_t)(k0 + i) * 1024];
        *(half8*)&Ws[wc][wk] = wh;
        __syncthreads();
        half8 af = *(const half8*)&As[16 * w + c][g * 8];
        #pragma unroll
        for (int j = 0; j < 4; j++) {
            half8 bf = *(const half8*)&Ws[16 * j + c][g * 8];
            acc[j] = __builtin_amdgcn_mfma_f32_16x16x32_f16(af, bf, acc[j], 0, 0, 0);
        }
        __syncthreads();
    }
    #pragma unroll
    for (int j = 0; j < 4; j++)
        #pragma unroll
        for (int rg = 0; rg < 4; rg++) {
            int r_g = row0 + 16 * w + g * 4 + rg, cg = col0 + 16 * j + c;
            out[(size_t)r_g * 1024 + cg] = acc[j][rg] + bias[cg];
        }
}

extern "C" void kernel_launch(void* const* d_in, const int* in_sizes, int n_in,
                              void* d_out, int out_size, void* d_ws, size_t ws_size,
                              hipStream_t stream)
{
    const float* x    = (const float*)d_in[0];
    const float* rel  = (const float*)d_in[1];
    const float* mem  = (const float*)d_in[2];
    const float* Wq   = (const float*)d_in[3];
    const float* Wk   = (const float*)d_in[4];
    const float* Wv   = (const float*)d_in[5];
    const float* Wr   = (const float*)d_in[6];
    const float* ub   = (const float*)d_in[7];
    const float* vb   = (const float*)d_in[8];
    const float* Wout = (const float*)d_in[9];
    const float* bout = (const float*)d_in[10];
    float* out = (float*)d_out;

    char* ws = (char*)d_ws;
    unsigned short* qu   = (unsigned short*)(ws);                    // 4 MB  bf16 [B,T,NH]
    _Float16*       qv   = (_Float16*)(ws + (4u << 20));             // 4 MB  fp16 [B,T,NH]
    unsigned short* kb   = (unsigned short*)(ws + (8u << 20));       // 8 MB  bf16 [B,S,NH]
    unsigned short* vtb  = (unsigned short*)(ws + (16u << 20));      // 8 MB  bf16 [B,N,H,S]
    _Float16*       rb   = (_Float16*)(ws + (24u << 20));            // 4.2MB fp16 [N,M,H]
    _Float16*       attn = (_Float16*)(ws + (29u << 20));            // 4 MB  fp16 [B,T,NH]
    _Float16*       bds  = (_Float16*)(ws + (34u << 20));            // 128MB fp16 [B,N,T,S]

    proj_kernel<<<dim3(32, 16), 256, 0, stream>>>(x,   Wq, 2048, 0, qu,  qv, ub, vb);
    proj_kernel<<<dim3(64, 16), 256, 0, stream>>>(mem, Wk, 4096, 1, kb,  nullptr, nullptr, nullptr);
    proj_kernel<<<dim3(64, 16), 256, 0, stream>>>(mem, Wv, 4096, 2, vtb, nullptr, nullptr, nullptr);
    proj_kernel<<<dim3(33, 16), 256, 0, stream>>>(rel, Wr, 2049, 3, nullptr, rb, nullptr, nullptr);
    bd_kernel<<<dim3(33, 16, 32), 256, 0, stream>>>(qv, rb, bds);
    flash_kernel<<<dim3(16, 32), 256, 0, stream>>>(qu, kb, vtb, bds, attn);
    out_kernel<<<dim3(32, 16), 256, 0, stream>>>(attn, Wout, bout, out);
}

// Round 2
// 437.793 us; speedup vs baseline: 1.0749x; 1.0749x over previous
//
#include <hip/hip_runtime.h>
#include <cmath>

#define LOG2E 1.4426950408889634f

typedef __attribute__((ext_vector_type(8))) short bf16x8;
typedef __attribute__((ext_vector_type(8))) _Float16 half8;
typedef __attribute__((ext_vector_type(4))) _Float16 half4;
typedef __attribute__((ext_vector_type(4))) float f32x4;

__device__ inline unsigned short bf16_rne(float f) {
    unsigned u = __builtin_bit_cast(unsigned, f);
    u += 0x7fff + ((u >> 16) & 1);
    return (unsigned short)(u >> 16);
}

// ---------------------------------------------------------------------------
// Projection GEMM: C[row, col] = sum_f A[row,f] * W[f,col], K = 1024 fixed.
// mode 0 = Q: writes qu bf16 [B,T,NH] (=acc+u_bias) and qv fp16 [B,T,NH] (=acc+v_bias)
// mode 3 = R: writes fp16 [N,M,H] (rows guarded to 2049)
// ---------------------------------------------------------------------------
__global__ __launch_bounds__(256) void proj_kernel(
    const float* __restrict__ A, const float* __restrict__ W,
    int nrows, int mode,
    unsigned short* __restrict__ o_b16, _Float16* __restrict__ o_f16,
    const float* __restrict__ ub, const float* __restrict__ vb)
{
    __shared__ _Float16 As[64][56];
    __shared__ _Float16 Ws[64][56];
    const int tid = threadIdx.x;
    const int lane = tid & 63, w = tid >> 6, c = lane & 15, g = lane >> 4;
    const int row0 = blockIdx.x * 64, col0 = blockIdx.y * 64;

    f32x4 acc[4] = {};
    const int ar = tid >> 2, akc = (tid & 3) * 8;
    const int wc = tid & 63, wk = (tid >> 6) * 8;
    const bool a_ok = (row0 + ar) < nrows;
    const float* Aptr = A + (size_t)(row0 + ar) * 1024 + akc;
    const float* Wptr = W + (size_t)wk * 1024 + col0 + wc;

    for (int k0 = 0; k0 < 1024; k0 += 32) {
        half8 ah;
        if (a_ok) {
            float4 t0 = *(const float4*)(Aptr + k0);
            float4 t1 = *(const float4*)(Aptr + k0 + 4);
            ah[0]=(_Float16)t0.x; ah[1]=(_Float16)t0.y; ah[2]=(_Float16)t0.z; ah[3]=(_Float16)t0.w;
            ah[4]=(_Float16)t1.x; ah[5]=(_Float16)t1.y; ah[6]=(_Float16)t1.z; ah[7]=(_Float16)t1.w;
        } else {
            for (int i = 0; i < 8; i++) ah[i] = (_Float16)0.f;
        }
        *(half8*)&As[ar][akc] = ah;
        half8 wh;
        #pragma unroll
        for (int i = 0; i < 8; i++) wh[i] = (_Float16)Wptr[(size_t)(k0 + i) * 1024];
        *(half8*)&Ws[wc][wk] = wh;
        __syncthreads();
        half8 af = *(const half8*)&As[16 * w + c][g * 8];
        #pragma unroll
        for (int j = 0; j < 4; j++) {
            half8 bf = *(const half8*)&Ws[16 * j + c][g * 8];
            acc[j] = __builtin_amdgcn_mfma_f32_16x16x32_f16(af, bf, acc[j], 0, 0, 0);
        }
        __syncthreads();
    }

    #pragma unroll
    for (int j = 0; j < 4; j++) {
        #pragma unroll
        for (int rg = 0; rg < 4; rg++) {
            int r_g = row0 + 16 * w + g * 4 + rg;
            int cg  = col0 + 16 * j + c;
            float v = acc[j][rg];
            if (mode == 0) {
                size_t o = (size_t)r_g * 1024 + cg;
                o_b16[o] = bf16_rne(v + ub[cg]);
                o_f16[o] = (_Float16)(v + vb[cg]);
            } else {
                if (r_g < nrows)
                    o_f16[((size_t)(cg >> 6) * 2049 + r_g) * 64 + (cg & 63)] = (_Float16)v;
            }
        }
    }
}

// ---------------------------------------------------------------------------
// Fused K+V projection: one A staging, two W tiles, two outputs.
// K -> bf16 [B,S,NH];  V -> bf16 transposed [B,N,H,S]
// ---------------------------------------------------------------------------
__global__ __launch_bounds__(256) void kv_proj_kernel(
    const float* __restrict__ A, const float* __restrict__ Wk,
    const float* __restrict__ Wv,
    unsigned short* __restrict__ kout, unsigned short* __restrict__ vtout)
{
    __shared__ _Float16 As[64][56];
    __shared__ _Float16 Wks[64][56];
    __shared__ _Float16 Wvs[64][56];
    const int tid = threadIdx.x;
    const int lane = tid & 63, w = tid >> 6, c = lane & 15, g = lane >> 4;
    const int row0 = blockIdx.x * 64, col0 = blockIdx.y * 64;

    f32x4 acck[4] = {}, accv[4] = {};
    const int ar = tid >> 2, akc = (tid & 3) * 8;
    const int wc = tid & 63, wk = (tid >> 6) * 8;
    const float* Aptr = A + (size_t)(row0 + ar) * 1024 + akc;
    const float* Wkp = Wk + (size_t)wk * 1024 + col0 + wc;
    const float* Wvp = Wv + (size_t)wk * 1024 + col0 + wc;

    for (int k0 = 0; k0 < 1024; k0 += 32) {
        float4 t0 = *(const float4*)(Aptr + k0);
        float4 t1 = *(const float4*)(Aptr + k0 + 4);
        half8 ah;
        ah[0]=(_Float16)t0.x; ah[1]=(_Float16)t0.y; ah[2]=(_Float16)t0.z; ah[3]=(_Float16)t0.w;
        ah[4]=(_Float16)t1.x; ah[5]=(_Float16)t1.y; ah[6]=(_Float16)t1.z; ah[7]=(_Float16)t1.w;
        *(half8*)&As[ar][akc] = ah;
        half8 wh, vh;
        #pragma unroll
        for (int i = 0; i < 8; i++) {
            wh[i] = (_Float16)Wkp[(size_t)(k0 + i) * 1024];
            vh[i] = (_Float16)Wvp[(size_t)(k0 + i) * 1024];
        }
        *(half8*)&Wks[wc][wk] = wh;
        *(half8*)&Wvs[wc][wk] = vh;
        __syncthreads();
        half8 af = *(const half8*)&As[16 * w + c][g * 8];
        #pragma unroll
        for (int j = 0; j < 4; j++) {
            half8 bk = *(const half8*)&Wks[16 * j + c][g * 8];
            half8 bv = *(const half8*)&Wvs[16 * j + c][g * 8];
            acck[j] = __builtin_amdgcn_mfma_f32_16x16x32_f16(af, bk, acck[j], 0, 0, 0);
            accv[j] = __builtin_amdgcn_mfma_f32_16x16x32_f16(af, bv, accv[j], 0, 0, 0);
        }
        __syncthreads();
    }

    #pragma unroll
    for (int j = 0; j < 4; j++) {
        #pragma unroll
        for (int rg = 0; rg < 4; rg++) {
            int r_g = row0 + 16 * w + g * 4 + rg;
            int cg  = col0 + 16 * j + c;
            kout[(size_t)r_g * 1024 + cg] = bf16_rne(acck[j][rg]);
            int b = r_g >> 11, s = r_g & 2047;
            vtout[((size_t)(b * 16 + (cg >> 6)) * 64 + (cg & 63)) * 2048 + s] = bf16_rne(accv[j][rg]);
        }
    }
}

// ---------------------------------------------------------------------------
// Fused flash attention with on-the-fly relative-shift bias.
// grid (T/64, B*N). Per s-tile: compute 64x128 BD tile via fp16 MFMA into
// LDS (transposed), gather shifted bias, online softmax, PV.
// diff = s - t:  diff<=1025 -> qv[t].r[diff+1023]; ==1026 -> 0;
//                >=1027 -> qv[t+1].r[diff-1027]
// Source region is a function of column idx = ss-tt+63 only, so one BD tile
// per s-tile suffices; per-j-tile A-frag select, per-lane r-row select.
// ---------------------------------------------------------------------------
__global__ __launch_bounds__(256) void flash_kernel(
    const unsigned short* __restrict__ qu, const _Float16* __restrict__ qv,
    const unsigned short* __restrict__ kg, const unsigned short* __restrict__ vt,
    const _Float16* __restrict__ rb, _Float16* __restrict__ attn)
{
    __shared__ unsigned short Ks[64][72];
    __shared__ unsigned short Vs[64][72];
    __shared__ unsigned short Ps[64][72];
    __shared__ _Float16 BDT[128][68];   // [idx][tt] transposed, wave-private in tt
    const int tid = threadIdx.x;
    const int lane = tid & 63, w = tid >> 6, c = lane & 15, g = lane >> 4;
    const int t0 = blockIdx.x * 64;
    const int bn = blockIdx.y, b = bn >> 4, n = bn & 15;

    // Q fragments: qu (bf16) for QK^T, qv (fp16) rows t and t+1 for BD
    const unsigned short* qp = qu + (size_t)(b * 1024 + t0 + 16 * w + c) * 1024 + n * 64 + g * 8;
    bf16x8 qf0 = *(const bf16x8*)qp;
    bf16x8 qf1 = *(const bf16x8*)(qp + 32);
    const _Float16* qvp = qv + (size_t)(b * 1024 + t0 + 16 * w + c) * 1024 + n * 64 + g * 8;
    half8 av0 = *(const half8*)qvp;
    half8 av1 = *(const half8*)(qvp + 32);
    int r2 = t0 + 16 * w + c + 1; if (r2 > 1023) r2 = 1023;  // row 1024 never used
    const _Float16* qvp2 = qv + (size_t)(b * 1024 + r2) * 1024 + n * 64 + g * 8;
    half8 aw0 = *(const half8*)qvp2;
    half8 aw1 = *(const half8*)(qvp2 + 32);

    const _Float16* rbase = rb + (size_t)n * 2049 * 64;

    f32x4 o[4] = {};
    float m_i[4], l_i[4];
    #pragma unroll
    for (int rg = 0; rg < 4; rg++) { m_i[rg] = -INFINITY; l_i[rg] = 0.f; }

    const int sr = tid >> 2, scc = (tid & 3) * 16;
    const unsigned short* kstage = kg + (size_t)(b * 2048 + sr) * 1024 + n * 64 + scc;
    const unsigned short* vstage = vt + ((size_t)bn * 64 + sr) * 2048 + scc;

    for (int s0 = 0; s0 < 2048; s0 += 64) {
        // ---- stage K/V tile ----
        *(uint4*)&Ks[sr][scc]     = *(const uint4*)(kstage + (size_t)s0 * 1024);
        *(uint4*)&Ks[sr][scc + 8] = *(const uint4*)(kstage + (size_t)s0 * 1024 + 8);
        *(uint4*)&Vs[sr][scc]     = *(const uint4*)(vstage + s0);
        *(uint4*)&Vs[sr][scc + 8] = *(const uint4*)(vstage + s0 + 8);

        // ---- BD tile: 64 rows x 128 idx-cols, wave w computes tt in [16w,16w+16) ----
        const int diff0 = s0 - t0;
        #pragma unroll
        for (int j = 0; j < 8; j++) {
            int u = diff0 + 16 * j;
            int sdc = u + c - 63;                 // diff for this column
            int mm;
            if (sdc <= 1026) { mm = u + 960 + c; if (mm > 2048) mm = 2048; }
            else mm = u + c - 1090;
            const _Float16* rp = rbase + (size_t)mm * 64 + g * 8;
            half8 rb0 = *(const half8*)rp;
            half8 rb1 = *(const half8*)(rp + 32);
            f32x4 z;
            if (u <= 1072) {                      // all-main j-tile
                f32x4 zm = {};
                zm = __builtin_amdgcn_mfma_f32_16x16x32_f16(av0, rb0, zm, 0, 0, 0);
                zm = __builtin_amdgcn_mfma_f32_16x16x32_f16(av1, rb1, zm, 0, 0, 0);
                z = zm;
            } else if (u >= 1104) {               // all-wrap j-tile
                f32x4 zw = {};
                zw = __builtin_amdgcn_mfma_f32_16x16x32_f16(aw0, rb0, zw, 0, 0, 0);
                zw = __builtin_amdgcn_mfma_f32_16x16x32_f16(aw1, rb1, zw, 0, 0, 0);
                z = zw;
            } else {                              // u == 1088: straddle
                f32x4 zm = {}, zw = {};
                zm = __builtin_amdgcn_mfma_f32_16x16x32_f16(av0, rb0, zm, 0, 0, 0);
                zm = __builtin_amdgcn_mfma_f32_16x16x32_f16(av1, rb1, zm, 0, 0, 0);
                zw = __builtin_amdgcn_mfma_f32_16x16x32_f16(aw0, rb0, zw, 0, 0, 0);
                zw = __builtin_amdgcn_mfma_f32_16x16x32_f16(aw1, rb1, zw, 0, 0, 0);
                z = (sdc >= 1027) ? zw : zm;
            }
            half4 hv;
            #pragma unroll
            for (int rg = 0; rg < 4; rg++) hv[rg] = (_Float16)z[rg];
            *(half4*)&BDT[16 * j + c][16 * w + 4 * g] = hv;   // wave-private rows
        }

        __syncthreads();

        // ---- logits = (QK^T + bias) * scale ----
        float lg[4][4];
        #pragma unroll
        for (int j = 0; j < 4; j++) {
            bf16x8 kf0 = *(const bf16x8*)&Ks[16 * j + c][g * 8];
            bf16x8 kf1 = *(const bf16x8*)&Ks[16 * j + c][32 + g * 8];
            f32x4 sa = {};
            sa = __builtin_amdgcn_mfma_f32_16x16x32_bf16(qf0, kf0, sa, 0, 0, 0);
            sa = __builtin_amdgcn_mfma_f32_16x16x32_bf16(qf1, kf1, sa, 0, 0, 0);
            #pragma unroll
            for (int rg = 0; rg < 4; rg++) {
                int tt = 16 * w + 4 * g + rg;
                int idx = 16 * j + c - tt + 63;           // [0,126]
                int diff = diff0 + 16 * j + c - tt;
                float bias = (diff == 1026) ? 0.f : (float)BDT[idx][tt];
                lg[j][rg] = (sa[rg] + bias) * 0.125f;
            }
        }

        // ---- online softmax ----
        float nm[4], al[4], rs[4];
        #pragma unroll
        for (int rg = 0; rg < 4; rg++) {
            float m2 = fmaxf(fmaxf(lg[0][rg], lg[1][rg]), fmaxf(lg[2][rg], lg[3][rg]));
            #pragma unroll
            for (int off = 1; off < 16; off <<= 1)
                m2 = fmaxf(m2, __shfl_xor(m2, off, 16));
            nm[rg] = fmaxf(m_i[rg], m2);
            al[rg] = exp2f((m_i[rg] - nm[rg]) * LOG2E);
            rs[rg] = 0.f;
        }
        #pragma unroll
        for (int j = 0; j < 4; j++) {
            #pragma unroll
            for (int rg = 0; rg < 4; rg++) {
                float p = exp2f((lg[j][rg] - nm[rg]) * LOG2E);
                rs[rg] += p;
                Ps[16 * w + g * 4 + rg][16 * j + c] = bf16_rne(p);
            }
        }
        #pragma unroll
        for (int rg = 0; rg < 4; rg++) {
            float s2 = rs[rg];
            #pragma unroll
            for (int off = 1; off < 16; off <<= 1)
                s2 += __shfl_xor(s2, off, 16);
            l_i[rg] = l_i[rg] * al[rg] + s2;
            m_i[rg] = nm[rg];
        }
        #pragma unroll
        for (int j = 0; j < 4; j++)
            #pragma unroll
            for (int rg = 0; rg < 4; rg++)
                o[j][rg] *= al[rg];

        bf16x8 pf0 = *(const bf16x8*)&Ps[16 * w + c][g * 8];
        bf16x8 pf1 = *(const bf16x8*)&Ps[16 * w + c][32 + g * 8];
        #pragma unroll
        for (int j = 0; j < 4; j++) {
            bf16x8 vf0 = *(const bf16x8*)&Vs[16 * j + c][g * 8];
            bf16x8 vf1 = *(const bf16x8*)&Vs[16 * j + c][32 + g * 8];
            o[j] = __builtin_amdgcn_mfma_f32_16x16x32_bf16(pf0, vf0, o[j], 0, 0, 0);
            o[j] = __builtin_amdgcn_mfma_f32_16x16x32_bf16(pf1, vf1, o[j], 0, 0, 0);
        }
        __syncthreads();
    }

    #pragma unroll
    for (int j = 0; j < 4; j++) {
        #pragma unroll
        for (int rg = 0; rg < 4; rg++) {
            int t = t0 + 16 * w + g * 4 + rg;
            float val = o[j][rg] / l_i[rg];
            attn[(size_t)(b * 1024 + t) * 1024 + n * 64 + 16 * j + c] = (_Float16)val;
        }
    }
}

// ---------------------------------------------------------------------------
// Output GEMM: out[bt,f] = sum_nh attn[bt,nh]*Wout[nh,f] + b_out[f]
// ---------------------------------------------------------------------------
__global__ __launch_bounds__(256) void out_kernel(
    const _Float16* __restrict__ A, const float* __restrict__ W,
    const float* __restrict__ bias, float* __restrict__ out)
{
    __shared__ _Float16 As[64][56];
    __shared__ _Float16 Ws[64][56];
    const int tid = threadIdx.x;
    const int lane = tid & 63, w = tid >> 6, c = lane & 15, g = lane >> 4;
    const int row0 = blockIdx.x * 64, col0 = blockIdx.y * 64;
    f32x4 acc[4] = {};
    const int ar = tid >> 2, akc = (tid & 3) * 8;
    const int wc = tid & 63, wk = (tid >> 6) * 8;
    const _Float16* Aptr = A + (size_t)(row0 + ar) * 1024 + akc;
    const float* Wptr = W + (size_t)wk * 1024 + col0 + wc;
    for (int k0 = 0; k0 < 1024; k0 += 32) {
        *(half8*)&As[ar][akc] = *(const half8*)(Aptr + k0);
        half8 wh;
        #pragma unroll
        for (int i = 0; i < 8; i++) wh[i] = (_Float16)Wptr[(size_t)(k0 + i) * 1024];
        *(half8*)&Ws[wc][wk] = wh;
        __syncthreads();
        half8 af = *(const half8*)&As[16 * w + c][g * 8];
        #pragma unroll
        for (int j = 0; j < 4; j++) {
            half8 bf = *(const half8*)&Ws[16 * j + c][g * 8];
            acc[j] = __builtin_amdgcn_mfma_f32_16x16x32_f16(af, bf, acc[j], 0, 0, 0);
        }
        __syncthreads();
    }
    #pragma unroll
    for (int j = 0; j < 4; j++)
        #pragma unroll
        for (int rg = 0; rg < 4; rg++) {
            int r_g = row0 + 16 * w + g * 4 + rg, cg = col0 + 16 * j + c;
            out[(size_t)r_g * 1024 + cg] = acc[j][rg] + bias[cg];
        }
}

extern "C" void kernel_launch(void* const* d_in, const int* in_sizes, int n_in,
                              void* d_out, int out_size, void* d_ws, size_t ws_size,
                              hipStream_t stream)
{
    const float* x    = (const float*)d_in[0];
    const float* rel  = (const float*)d_in[1];
    const float* mem  = (const float*)d_in[2];
    const float* Wq   = (const float*)d_in[3];
    const float* Wk   = (const float*)d_in[4];
    const float* Wv   = (const float*)d_in[5];
    const float* Wr   = (const float*)d_in[6];
    const float* ub   = (const float*)d_in[7];
    const float* vb   = (const float*)d_in[8];
    const float* Wout = (const float*)d_in[9];
    const float* bout = (const float*)d_in[10];
    float* out = (float*)d_out;

    char* ws = (char*)d_ws;
    unsigned short* qu   = (unsigned short*)(ws);                    // 4 MB  bf16 [B,T,NH]
    _Float16*       qv   = (_Float16*)(ws + (4u << 20));             // 4 MB  fp16 [B,T,NH]
    unsigned short* kb   = (unsigned short*)(ws + (8u << 20));       // 8 MB  bf16 [B,S,NH]
    unsigned short* vtb  = (unsigned short*)(ws + (16u << 20));      // 8 MB  bf16 [B,N,H,S]
    _Float16*       rb   = (_Float16*)(ws + (24u << 20));            // 4.2MB fp16 [N,M,H]
    _Float16*       attn = (_Float16*)(ws + (29u << 20));            // 4 MB  fp16 [B,T,NH]

    proj_kernel<<<dim3(32, 16), 256, 0, stream>>>(x,   Wq, 2048, 0, qu,  qv, ub, vb);
    kv_proj_kernel<<<dim3(64, 16), 256, 0, stream>>>(mem, Wk, Wv, kb, vtb);
    proj_kernel<<<dim3(33, 16), 256, 0, stream>>>(rel, Wr, 2049, 3, nullptr, rb, nullptr, nullptr);
    flash_kernel<<<dim3(16, 32), 256, 0, stream>>>(qu, qv, kb, vtb, rb, attn);
    out_kernel<<<dim3(32, 16), 256, 0, stream>>>(attn, Wout, bout, out);
}

// Round 3
// 363.925 us; speedup vs baseline: 1.2931x; 1.2030x over previous
//
#include <hip/hip_runtime.h>
#include <cmath>

#define C_SCALE 0.18033688011112042f   // 0.125 * log2(e)

typedef __attribute__((ext_vector_type(8))) short bf16x8;
typedef __attribute__((ext_vector_type(8))) _Float16 half8;
typedef __attribute__((ext_vector_type(4))) _Float16 half4;
typedef __attribute__((ext_vector_type(4))) float f32x4;

__device__ inline unsigned short bf16_rne(float f) {
    unsigned u = __builtin_bit_cast(unsigned, f);
    u += 0x7fff + ((u >> 16) & 1);
    return (unsigned short)(u >> 16);
}

// ---------------------------------------------------------------------------
// Projection GEMM: C[row, col] = sum_f A[row,f] * W[f,col], K = 1024 fixed.
// mode 0 = Q: qu bf16 (=acc+u_bias), qv fp16 (=(acc+v_bias)*C_SCALE)
// mode 3 = R: fp16 [N,M,H] (rows guarded to 2049)
// ---------------------------------------------------------------------------
__global__ __launch_bounds__(256) void proj_kernel(
    const float* __restrict__ A, const float* __restrict__ W,
    int nrows, int mode,
    unsigned short* __restrict__ o_b16, _Float16* __restrict__ o_f16,
    const float* __restrict__ ub, const float* __restrict__ vb)
{
    __shared__ _Float16 As[64][56];
    __shared__ _Float16 Ws[64][56];
    const int tid = threadIdx.x;
    const int lane = tid & 63, w = tid >> 6, c = lane & 15, g = lane >> 4;
    const int row0 = blockIdx.x * 64, col0 = blockIdx.y * 64;

    f32x4 acc[4] = {};
    const int ar = tid >> 2, akc = (tid & 3) * 8;
    const int wc = tid & 63, wk = (tid >> 6) * 8;
    const bool a_ok = (row0 + ar) < nrows;
    const float* Aptr = A + (size_t)(row0 + ar) * 1024 + akc;
    const float* Wptr = W + (size_t)wk * 1024 + col0 + wc;

    for (int k0 = 0; k0 < 1024; k0 += 32) {
        half8 ah;
        if (a_ok) {
            float4 t0 = *(const float4*)(Aptr + k0);
            float4 t1 = *(const float4*)(Aptr + k0 + 4);
            ah[0]=(_Float16)t0.x; ah[1]=(_Float16)t0.y; ah[2]=(_Float16)t0.z; ah[3]=(_Float16)t0.w;
            ah[4]=(_Float16)t1.x; ah[5]=(_Float16)t1.y; ah[6]=(_Float16)t1.z; ah[7]=(_Float16)t1.w;
        } else {
            for (int i = 0; i < 8; i++) ah[i] = (_Float16)0.f;
        }
        *(half8*)&As[ar][akc] = ah;
        half8 wh;
        #pragma unroll
        for (int i = 0; i < 8; i++) wh[i] = (_Float16)Wptr[(size_t)(k0 + i) * 1024];
        *(half8*)&Ws[wc][wk] = wh;
        __syncthreads();
        half8 af = *(const half8*)&As[16 * w + c][g * 8];
        #pragma unroll
        for (int j = 0; j < 4; j++) {
            half8 bf = *(const half8*)&Ws[16 * j + c][g * 8];
            acc[j] = __builtin_amdgcn_mfma_f32_16x16x32_f16(af, bf, acc[j], 0, 0, 0);
        }
        __syncthreads();
    }

    #pragma unroll
    for (int j = 0; j < 4; j++) {
        #pragma unroll
        for (int rg = 0; rg < 4; rg++) {
            int r_g = row0 + 16 * w + g * 4 + rg;
            int cg  = col0 + 16 * j + c;
            float v = acc[j][rg];
            if (mode == 0) {
                size_t o = (size_t)r_g * 1024 + cg;
                o_b16[o] = bf16_rne(v + ub[cg]);
                o_f16[o] = (_Float16)((v + vb[cg]) * C_SCALE);
            } else {
                if (r_g < nrows)
                    o_f16[((size_t)(cg >> 6) * 2049 + r_g) * 64 + (cg & 63)] = (_Float16)v;
            }
        }
    }
}

// ---------------------------------------------------------------------------
// Fused K+V projection. K -> bf16 [B,S,NH];  V -> bf16 transposed [B,N,H,S]
// ---------------------------------------------------------------------------
__global__ __launch_bounds__(256) void kv_proj_kernel(
    const float* __restrict__ A, const float* __restrict__ Wk,
    const float* __restrict__ Wv,
    unsigned short* __restrict__ kout, unsigned short* __restrict__ vtout)
{
    __shared__ _Float16 As[64][56];
    __shared__ _Float16 Wks[64][56];
    __shared__ _Float16 Wvs[64][56];
    const int tid = threadIdx.x;
    const int lane = tid & 63, w = tid >> 6, c = lane & 15, g = lane >> 4;
    const int row0 = blockIdx.x * 64, col0 = blockIdx.y * 64;

    f32x4 acck[4] = {}, accv[4] = {};
    const int ar = tid >> 2, akc = (tid & 3) * 8;
    const int wc = tid & 63, wk = (tid >> 6) * 8;
    const float* Aptr = A + (size_t)(row0 + ar) * 1024 + akc;
    const float* Wkp = Wk + (size_t)wk * 1024 + col0 + wc;
    const float* Wvp = Wv + (size_t)wk * 1024 + col0 + wc;

    for (int k0 = 0; k0 < 1024; k0 += 32) {
        float4 t0 = *(const float4*)(Aptr + k0);
        float4 t1 = *(const float4*)(Aptr + k0 + 4);
        half8 ah;
        ah[0]=(_Float16)t0.x; ah[1]=(_Float16)t0.y; ah[2]=(_Float16)t0.z; ah[3]=(_Float16)t0.w;
        ah[4]=(_Float16)t1.x; ah[5]=(_Float16)t1.y; ah[6]=(_Float16)t1.z; ah[7]=(_Float16)t1.w;
        *(half8*)&As[ar][akc] = ah;
        half8 wh, vh;
        #pragma unroll
        for (int i = 0; i < 8; i++) {
            wh[i] = (_Float16)Wkp[(size_t)(k0 + i) * 1024];
            vh[i] = (_Float16)Wvp[(size_t)(k0 + i) * 1024];
        }
        *(half8*)&Wks[wc][wk] = wh;
        *(half8*)&Wvs[wc][wk] = vh;
        __syncthreads();
        half8 af = *(const half8*)&As[16 * w + c][g * 8];
        #pragma unroll
        for (int j = 0; j < 4; j++) {
            half8 bk = *(const half8*)&Wks[16 * j + c][g * 8];
            half8 bv = *(const half8*)&Wvs[16 * j + c][g * 8];
            acck[j] = __builtin_amdgcn_mfma_f32_16x16x32_f16(af, bk, acck[j], 0, 0, 0);
            accv[j] = __builtin_amdgcn_mfma_f32_16x16x32_f16(af, bv, accv[j], 0, 0, 0);
        }
        __syncthreads();
    }

    #pragma unroll
    for (int j = 0; j < 4; j++) {
        #pragma unroll
        for (int rg = 0; rg < 4; rg++) {
            int r_g = row0 + 16 * w + g * 4 + rg;
            int cg  = col0 + 16 * j + c;
            kout[(size_t)r_g * 1024 + cg] = bf16_rne(acck[j][rg]);
            int b = r_g >> 11, s = r_g & 2047;
            vtout[((size_t)(b * 16 + (cg >> 6)) * 64 + (cg & 63)) * 2048 + s] = bf16_rne(accv[j][rg]);
        }
    }
}

// ---------------------------------------------------------------------------
// Flash attention, s-split x4, unnormalized softmax (no online max),
// incremental circular BD window (128 cols, slot = D & 127).
// D = s - t. D<=1025: qv[t].r[D+1023]; D==1026: 0; D>=1027: qv[t+1].r[D-1027].
// BDT pre-scaled by C_SCALE (folded into qv at projection time).
// Outputs unnormalized o (fp32) + row sums l per partition.
// ---------------------------------------------------------------------------
__global__ __launch_bounds__(256) void flash_kernel(
    const unsigned short* __restrict__ qu, const _Float16* __restrict__ qv,
    const unsigned short* __restrict__ kg, const unsigned short* __restrict__ vt,
    const _Float16* __restrict__ rb, float* __restrict__ po, float* __restrict__ pl)
{
    __shared__ unsigned short Ks[64][70];
    __shared__ unsigned short Vs[64][70];
    __shared__ unsigned short Ps[64][70];
    __shared__ _Float16 BDT[128][70];
    const int tid = threadIdx.x;
    const int lane = tid & 63, w = tid >> 6, c = lane & 15, g = lane >> 4;
    const int t0 = blockIdx.x * 64;
    const int bn = blockIdx.y, b = bn >> 4, n = bn & 15;
    const int part = blockIdx.z;
    const int s_start = part * 512;

    const unsigned short* qp = qu + (size_t)(b * 1024 + t0 + 16 * w + c) * 1024 + n * 64 + g * 8;
    bf16x8 qf0 = *(const bf16x8*)qp;
    bf16x8 qf1 = *(const bf16x8*)(qp + 32);
    const _Float16* qvp = qv + (size_t)(b * 1024 + t0 + 16 * w + c) * 1024 + n * 64 + g * 8;
    half8 av0 = *(const half8*)qvp;
    half8 av1 = *(const half8*)(qvp + 32);
    int r2 = t0 + 16 * w + c + 1; if (r2 > 1023) r2 = 1023;   // row t=1023 never uses wrap
    const _Float16* qvp2 = qv + (size_t)(b * 1024 + r2) * 1024 + n * 64 + g * 8;
    half8 aw0 = *(const half8*)qvp2;
    half8 aw1 = *(const half8*)(qvp2 + 32);

    const _Float16* rbase = rb + (size_t)n * 2049 * 64;

    f32x4 o[4] = {};
    float l_i[4] = {0.f, 0.f, 0.f, 0.f};

    const int sr = tid >> 2, scc = (tid & 3) * 16;
    const unsigned short* kstage = kg + (size_t)(b * 2048 + s_start + sr) * 1024 + n * 64 + scc;
    const unsigned short* vstage = vt + ((size_t)bn * 64 + sr) * 2048 + s_start + scc;

    // computes nj 16-col BD tiles starting at column D = Dbase, writes BDT slots
    auto bd_tile = [&](int Dbase, int nj) {
        for (int j = 0; j < nj; j++) {
            int Dl = Dbase + 16 * j + c;      // per-lane column D
            int Dmin = Dbase + 16 * j;
            int mm;
            if (Dl <= 1026) { mm = Dl + 1023; if (mm > 2048) mm = 2048; }
            else mm = Dl - 1027;
            const _Float16* rp = rbase + (size_t)mm * 64 + g * 8;
            half8 rb0 = *(const half8*)rp;
            half8 rb1 = *(const half8*)(rp + 32);
            f32x4 z;
            if (Dmin + 15 <= 1026) {
                f32x4 zm = {};
                zm = __builtin_amdgcn_mfma_f32_16x16x32_f16(av0, rb0, zm, 0, 0, 0);
                zm = __builtin_amdgcn_mfma_f32_16x16x32_f16(av1, rb1, zm, 0, 0, 0);
                z = zm;
            } else if (Dmin >= 1027) {
                f32x4 zw = {};
                zw = __builtin_amdgcn_mfma_f32_16x16x32_f16(aw0, rb0, zw, 0, 0, 0);
                zw = __builtin_amdgcn_mfma_f32_16x16x32_f16(aw1, rb1, zw, 0, 0, 0);
                z = zw;
            } else {
                f32x4 zm = {}, zw = {};
                zm = __builtin_amdgcn_mfma_f32_16x16x32_f16(av0, rb0, zm, 0, 0, 0);
                zm = __builtin_amdgcn_mfma_f32_16x16x32_f16(av1, rb1, zm, 0, 0, 0);
                zw = __builtin_amdgcn_mfma_f32_16x16x32_f16(aw0, rb0, zw, 0, 0, 0);
                zw = __builtin_amdgcn_mfma_f32_16x16x32_f16(aw1, rb1, zw, 0, 0, 0);
                z = (Dl >= 1027) ? zw : zm;
            }
            half4 hv;
            #pragma unroll
            for (int rg = 0; rg < 4; rg++) hv[rg] = (_Float16)z[rg];
            *(half4*)&BDT[Dl & 127][16 * w + 4 * g] = hv;     // wave-private cols
        }
    };

    for (int kk = 0; kk < 8; kk++) {
        const int s0 = s_start + kk * 64;
        const int diff0 = s0 - t0;

        *(uint4*)&Ks[sr][scc]     = *(const uint4*)(kstage + (size_t)(kk * 64) * 1024);
        *(uint4*)&Ks[sr][scc + 8] = *(const uint4*)(kstage + (size_t)(kk * 64) * 1024 + 8);
        *(uint4*)&Vs[sr][scc]     = *(const uint4*)(vstage + kk * 64);
        *(uint4*)&Vs[sr][scc + 8] = *(const uint4*)(vstage + kk * 64 + 8);

        if (kk == 0) bd_tile(diff0 - 63, 8);   // fill full 128-col window
        else         bd_tile(diff0 + 1, 4);    // 64 new cols

        __syncthreads();

        #pragma unroll
        for (int j = 0; j < 4; j++) {
            bf16x8 kf0 = *(const bf16x8*)&Ks[16 * j + c][g * 8];
            bf16x8 kf1 = *(const bf16x8*)&Ks[16 * j + c][32 + g * 8];
            f32x4 sa = {};
            sa = __builtin_amdgcn_mfma_f32_16x16x32_bf16(qf0, kf0, sa, 0, 0, 0);
            sa = __builtin_amdgcn_mfma_f32_16x16x32_bf16(qf1, kf1, sa, 0, 0, 0);
            #pragma unroll
            for (int rg = 0; rg < 4; rg++) {
                int tt = 16 * w + 4 * g + rg;
                int D = diff0 + 16 * j + c - tt;
                float bdt = (float)BDT[D & 127][tt];
                bdt = (D == 1026) ? 0.f : bdt;
                float p = exp2f(fmaf(sa[rg], C_SCALE, bdt));
                l_i[rg] += p;
                Ps[tt][16 * j + c] = bf16_rne(p);
            }
        }

        bf16x8 pf0 = *(const bf16x8*)&Ps[16 * w + c][g * 8];
        bf16x8 pf1 = *(const bf16x8*)&Ps[16 * w + c][32 + g * 8];
        #pragma unroll
        for (int j = 0; j < 4; j++) {
            bf16x8 vf0 = *(const bf16x8*)&Vs[16 * j + c][g * 8];
            bf16x8 vf1 = *(const bf16x8*)&Vs[16 * j + c][32 + g * 8];
            o[j] = __builtin_amdgcn_mfma_f32_16x16x32_bf16(pf0, vf0, o[j], 0, 0, 0);
            o[j] = __builtin_amdgcn_mfma_f32_16x16x32_bf16(pf1, vf1, o[j], 0, 0, 0);
        }
        __syncthreads();
    }

    #pragma unroll
    for (int rg = 0; rg < 4; rg++) {
        float s2 = l_i[rg];
        #pragma unroll
        for (int off = 1; off < 16; off <<= 1)
            s2 += __shfl_xor(s2, off, 16);
        int t = t0 + 16 * w + 4 * g + rg;
        size_t rowb = ((size_t)part * 32 + bn) * 1024 + t;
        if (c == 0) pl[rowb] = s2;
        #pragma unroll
        for (int j = 0; j < 4; j++)
            po[rowb * 64 + 16 * j + c] = o[j][rg];
    }
}

// ---------------------------------------------------------------------------
// Combine partitions: attn = (sum_p o_p) / (sum_p l_p), fp16 [B,T,NH]
// ---------------------------------------------------------------------------
__global__ __launch_bounds__(256) void combine_kernel(
    const float* __restrict__ po, const float* __restrict__ pl,
    _Float16* __restrict__ attn)
{
    int f = blockIdx.x * 256 + threadIdx.x;       // B*N*T*H = 2M
    int h = f & 63, t = (f >> 6) & 1023, bn = f >> 16;
    float os = 0.f, ls = 0.f;
    #pragma unroll
    for (int p = 0; p < 4; p++) {
        size_t rowb = ((size_t)p * 32 + bn) * 1024 + t;
        os += po[rowb * 64 + h];
        ls += pl[rowb];
    }
    int b = bn >> 4, n = bn & 15;
    attn[((size_t)b * 1024 + t) * 1024 + n * 64 + h] = (_Float16)(os / ls);
}

// ---------------------------------------------------------------------------
// Output GEMM: out[bt,f] = sum_nh attn[bt,nh]*Wout[nh,f] + b_out[f]
// ---------------------------------------------------------------------------
__global__ __launch_bounds__(256) void out_kernel(
    const _Float16* __restrict__ A, const float* __restrict__ W,
    const float* __restrict__ bias, float* __restrict__ out)
{
    __shared__ _Float16 As[64][56];
    __shared__ _Float16 Ws[64][56];
    const int tid = threadIdx.x;
    const int lane = tid & 63, w = tid >> 6, c = lane & 15, g = lane >> 4;
    const int row0 = blockIdx.x * 64, col0 = blockIdx.y * 64;
    f32x4 acc[4] = {};
    const int ar = tid >> 2, akc = (tid & 3) * 8;
    const int wc = tid & 63, wk = (tid >> 6) * 8;
    const _Float16* Aptr = A + (size_t)(row0 + ar) * 1024 + akc;
    const float* Wptr = W + (size_t)wk * 1024 + col0 + wc;
    for (int k0 = 0; k0 < 1024; k0 += 32) {
        *(half8*)&As[ar][akc] = *(const half8*)(Aptr + k0);
        half8 wh;
        #pragma unroll
        for (int i = 0; i < 8; i++) wh[i] = (_Float16)Wptr[(size_t)(k0 + i) * 1024];
        *(half8*)&Ws[wc][wk] = wh;
        __syncthreads();
        half8 af = *(const half8*)&As[16 * w + c][g * 8];
        #pragma unroll
        for (int j = 0; j < 4; j++) {
            half8 bf = *(const half8*)&Ws[16 * j + c][g * 8];
            acc[j] = __builtin_amdgcn_mfma_f32_16x16x32_f16(af, bf, acc[j], 0, 0, 0);
        }
        __syncthreads();
    }
    #pragma unroll
    for (int j = 0; j < 4; j++)
        #pragma unroll
        for (int rg = 0; rg < 4; rg++) {
            int r_g = row0 + 16 * w + g * 4 + rg, cg = col0 + 16 * j + c;
            out[(size_t)r_g * 1024 + cg] = acc[j][rg] + bias[cg];
        }
}

extern "C" void kernel_launch(void* const* d_in, const int* in_sizes, int n_in,
                              void* d_out, int out_size, void* d_ws, size_t ws_size,
                              hipStream_t stream)
{
    const float* x    = (const float*)d_in[0];
    const float* rel  = (const float*)d_in[1];
    const float* mem  = (const float*)d_in[2];
    const float* Wq   = (const float*)d_in[3];
    const float* Wk   = (const float*)d_in[4];
    const float* Wv   = (const float*)d_in[5];
    const float* Wr   = (const float*)d_in[6];
    const float* ub   = (const float*)d_in[7];
    const float* vb   = (const float*)d_in[8];
    const float* Wout = (const float*)d_in[9];
    const float* bout = (const float*)d_in[10];
    float* out = (float*)d_out;

    char* ws = (char*)d_ws;
    unsigned short* qu   = (unsigned short*)(ws);                    // 4 MB   bf16 [B,T,NH]
    _Float16*       qv   = (_Float16*)(ws + (4ull << 20));           // 4 MB   fp16 [B,T,NH] (*C_SCALE)
    unsigned short* kb   = (unsigned short*)(ws + (8ull << 20));     // 8 MB   bf16 [B,S,NH]
    unsigned short* vtb  = (unsigned short*)(ws + (16ull << 20));    // 8 MB   bf16 [B,N,H,S]
    _Float16*       rb   = (_Float16*)(ws + (24ull << 20));          // 4.2 MB fp16 [N,M,H]
    _Float16*       attn = (_Float16*)(ws + (29ull << 20));          // 4 MB   fp16 [B,T,NH]
    float*          po   = (float*)(ws + (33ull << 20));             // 33.6MB fp32 [4,BN,T,H]
    float*          pl   = (float*)(ws + (68ull << 20));             // 0.5 MB fp32 [4,BN,T]

    proj_kernel<<<dim3(32, 16), 256, 0, stream>>>(x,   Wq, 2048, 0, qu,  qv, ub, vb);
    kv_proj_kernel<<<dim3(64, 16), 256, 0, stream>>>(mem, Wk, Wv, kb, vtb);
    proj_kernel<<<dim3(33, 16), 256, 0, stream>>>(rel, Wr, 2049, 3, nullptr, rb, nullptr, nullptr);
    flash_kernel<<<dim3(16, 32, 4), 256, 0, stream>>>(qu, qv, kb, vtb, rb, po, pl);
    combine_kernel<<<dim3(8192), 256, 0, stream>>>(po, pl, attn);
    out_kernel<<<dim3(32, 16), 256, 0, stream>>>(attn, Wout, bout, out);
}

// Round 4
// 319.995 us; speedup vs baseline: 1.4707x; 1.1373x over previous
//
#include <hip/hip_runtime.h>
#include <cmath>

#define C_SCALE 0.18033688011112042f   // 0.125 * log2(e)

typedef __attribute__((ext_vector_type(8))) short bf16x8;
typedef __attribute__((ext_vector_type(8))) _Float16 half8;
typedef __attribute__((ext_vector_type(4))) _Float16 half4;
typedef __attribute__((ext_vector_type(4))) float f32x4;
typedef __attribute__((ext_vector_type(4))) unsigned short us4;

__device__ inline unsigned short bf16_rne(float f) {
    unsigned u = __builtin_bit_cast(unsigned, f);
    u += 0x7fff + ((u >> 16) & 1);
    return (unsigned short)(u >> 16);
}

// async global->LDS DMA, 16B per lane; LDS dest = wave-uniform base + lane*16
__device__ inline void lds_dma16(const _Float16* g, _Float16* l) {
    __builtin_amdgcn_global_load_lds(
        (__attribute__((address_space(1))) void*)(void*)g,
        (__attribute__((address_space(3))) void*)(void*)l, 16, 0, 0);
}

// ---------------------------------------------------------------------------
// Prep 1: fp32 -> fp16 for x (2M), mem (4M), rel (2049*1024)
// ---------------------------------------------------------------------------
__global__ __launch_bounds__(256) void convert_kernel(
    const float* __restrict__ x, const float* __restrict__ mem,
    const float* __restrict__ rel,
    _Float16* __restrict__ x16, _Float16* __restrict__ mem16,
    _Float16* __restrict__ rel16)
{
    size_t i = ((size_t)blockIdx.x * 256 + threadIdx.x) * 8;
    if (i >= 8389632ull) return;
    const float* src; _Float16* dst; size_t off;
    if (i < 2097152ull)      { src = x;   dst = x16;   off = i; }
    else if (i < 6291456ull) { src = mem; dst = mem16; off = i - 2097152ull; }
    else                     { src = rel; dst = rel16; off = i - 6291456ull; }
    float4 a = *(const float4*)(src + off);
    float4 b = *(const float4*)(src + off + 4);
    half8 h;
    h[0]=(_Float16)a.x; h[1]=(_Float16)a.y; h[2]=(_Float16)a.z; h[3]=(_Float16)a.w;
    h[4]=(_Float16)b.x; h[5]=(_Float16)b.y; h[6]=(_Float16)b.z; h[7]=(_Float16)b.w;
    *(half8*)(dst + off) = h;
}

// ---------------------------------------------------------------------------
// Prep 2: transpose 1024x1024 fp32 -> fp16 for the 5 weight matrices.
// Wt[col][k] = W[k][col]
// ---------------------------------------------------------------------------
__global__ __launch_bounds__(256) void transpose_kernel(
    const float* __restrict__ s0, const float* __restrict__ s1,
    const float* __restrict__ s2, const float* __restrict__ s3,
    const float* __restrict__ s4,
    _Float16* __restrict__ d0, _Float16* __restrict__ d1,
    _Float16* __restrict__ d2, _Float16* __restrict__ d3,
    _Float16* __restrict__ d4)
{
    __shared__ _Float16 T[64][72];
    const int z = blockIdx.z;
    const float* src = z == 0 ? s0 : z == 1 ? s1 : z == 2 ? s2 : z == 3 ? s3 : s4;
    _Float16*    dst = z == 0 ? d0 : z == 1 ? d1 : z == 2 ? d2 : z == 3 ? d3 : d4;
    const int tid = threadIdx.x;
    const int r0 = blockIdx.x * 64, c0 = blockIdx.y * 64;
    const int r = tid >> 4, c4 = (tid & 15) * 4;
    #pragma unroll
    for (int rr = 0; rr < 64; rr += 16) {
        float4 v = *(const float4*)(src + (size_t)(r0 + r + rr) * 1024 + c0 + c4);
        T[c4 + 0][r + rr] = (_Float16)v.x;
        T[c4 + 1][r + rr] = (_Float16)v.y;
        T[c4 + 2][r + rr] = (_Float16)v.z;
        T[c4 + 3][r + rr] = (_Float16)v.w;
    }
    __syncthreads();
    const int orow = tid >> 2, seg = (tid & 3) * 16;
    half8 h0 = *(const half8*)&T[orow][seg];
    half8 h1 = *(const half8*)&T[orow][seg + 8];
    *(half8*)(dst + (size_t)(c0 + orow) * 1024 + r0 + seg)     = h0;
    *(half8*)(dst + (size_t)(c0 + orow) * 1024 + r0 + seg + 8) = h1;
}

// ---------------------------------------------------------------------------
// Unified projection GEMM (fp16 x fp16, lds-dma staged, BK=64, XOR swizzle).
// grid.x regions: [0,32) Q from x16; [32,96) K+V from mem16 (two B tiles);
// [96,129) R from rel16. grid.y = 16 col-tiles.
// ---------------------------------------------------------------------------
__global__ __launch_bounds__(256) void proj2_kernel(
    const _Float16* __restrict__ x16, const _Float16* __restrict__ mem16,
    const _Float16* __restrict__ rel16,
    const _Float16* __restrict__ Wqt, const _Float16* __restrict__ Wkt,
    const _Float16* __restrict__ Wvt, const _Float16* __restrict__ Wrt,
    const float* __restrict__ ub, const float* __restrict__ vb,
    unsigned short* __restrict__ qu, _Float16* __restrict__ qv,
    unsigned short* __restrict__ kb, unsigned short* __restrict__ vtb,
    _Float16* __restrict__ rb)
{
    alignas(16) __shared__ _Float16 As[4096];
    alignas(16) __shared__ _Float16 Bs1[4096];
    alignas(16) __shared__ _Float16 Bs2[4096];
    const int tid = threadIdx.x;
    const int lane = tid & 63, w = tid >> 6, c = lane & 15, g = lane >> 4;
    const int bx = blockIdx.x, col0 = blockIdx.y * 64;

    int mode, row0, rowmax;
    const _Float16* Ap; const _Float16* B1p; const _Float16* B2p = nullptr;
    if (bx < 32)       { mode = 0; row0 = bx * 64;        rowmax = 2047; Ap = x16;   B1p = Wqt; }
    else if (bx < 96)  { mode = 1; row0 = (bx - 32) * 64; rowmax = 4095; Ap = mem16; B1p = Wkt; B2p = Wvt; }
    else               { mode = 2; row0 = (bx - 96) * 64; rowmax = 2048; Ap = rel16; B1p = Wrt; }

    // staging geometry: wave w, call q covers rows 16w+8q .. +8; lane: row += lane>>3,
    // phys chunk = lane&7, logical chunk = phys ^ (row&7)
    const int srow = 16 * w + (lane >> 3);
    const int phys = lane & 7;
    f32x4 acc1[4] = {}, acc2[4] = {};

    for (int k0 = 0; k0 < 1024; k0 += 64) {
        #pragma unroll
        for (int q = 0; q < 2; q++) {
            int row = srow + 8 * q;
            int log = phys ^ (row & 7);
            int ar = row0 + row; if (ar > rowmax) ar = rowmax;
            lds_dma16(Ap + (size_t)ar * 1024 + k0 + log * 8, &As[(16 * w + 8 * q) * 64]);
            lds_dma16(B1p + (size_t)(col0 + row) * 1024 + k0 + log * 8, &Bs1[(16 * w + 8 * q) * 64]);
            if (mode == 1)
                lds_dma16(B2p + (size_t)(col0 + row) * 1024 + k0 + log * 8, &Bs2[(16 * w + 8 * q) * 64]);
        }
        __syncthreads();
        #pragma unroll
        for (int s = 0; s < 2; s++) {
            const int pc = ((4 * s + g) ^ (c & 7)) * 8;
            half8 af = *(const half8*)&As[(16 * w + c) * 64 + pc];
            #pragma unroll
            for (int j = 0; j < 4; j++) {
                half8 b1 = *(const half8*)&Bs1[(16 * j + c) * 64 + pc];
                acc1[j] = __builtin_amdgcn_mfma_f32_16x16x32_f16(af, b1, acc1[j], 0, 0, 0);
                if (mode == 1) {
                    half8 b2 = *(const half8*)&Bs2[(16 * j + c) * 64 + pc];
                    acc2[j] = __builtin_amdgcn_mfma_f32_16x16x32_f16(af, b2, acc2[j], 0, 0, 0);
                }
            }
        }
        __syncthreads();
    }

    #pragma unroll
    for (int j = 0; j < 4; j++) {
        const int cg = col0 + 16 * j + c;
        if (mode == 0) {
            float u = ub[cg], v = vb[cg];
            #pragma unroll
            for (int rg = 0; rg < 4; rg++) {
                int r_g = row0 + 16 * w + g * 4 + rg;
                size_t o = (size_t)r_g * 1024 + cg;
                qu[o] = bf16_rne(acc1[j][rg] + u);
                qv[o] = (_Float16)((acc1[j][rg] + v) * C_SCALE);
            }
        } else if (mode == 1) {
            int rbase = row0 + 16 * w + g * 4;
            us4 pk;
            #pragma unroll
            for (int rg = 0; rg < 4; rg++) {
                kb[(size_t)(rbase + rg) * 1024 + cg] = bf16_rne(acc1[j][rg]);
                pk[rg] = bf16_rne(acc2[j][rg]);
            }
            int b = rbase >> 11, s = rbase & 2047;
            *(us4*)&vtb[((size_t)(b * 16 + (cg >> 6)) * 64 + (cg & 63)) * 2048 + s] = pk;
        } else {
            #pragma unroll
            for (int rg = 0; rg < 4; rg++) {
                int r_g = row0 + 16 * w + g * 4 + rg;
                if (r_g < 2049)
                    rb[((size_t)(cg >> 6) * 2049 + r_g) * 64 + (cg & 63)] = (_Float16)acc1[j][rg];
            }
        }
    }
}

// ---------------------------------------------------------------------------
// Flash attention, s-split x4, unnormalized softmax, incremental circular BD.
// 1D grid 2048 with XCD-aware decode: p=id&127 -> (bn,part), t=id>>7, so all
// 16 t-blocks of one (bn,part) share an XCD -> K/V/r stay L2-resident.
// D==1026 zeroed once at BD-write time (slot is unique in the 128-window).
// ---------------------------------------------------------------------------
__global__ __launch_bounds__(256) void flash_kernel(
    const unsigned short* __restrict__ qu, const _Float16* __restrict__ qv,
    const unsigned short* __restrict__ kg, const unsigned short* __restrict__ vt,
    const _Float16* __restrict__ rb, float* __restrict__ po, float* __restrict__ pl)
{
    __shared__ unsigned short Ks[64][70];
    __shared__ unsigned short Vs[64][70];
    __shared__ unsigned short Ps[64][70];
    __shared__ _Float16 BDT[128][70];
    const int tid = threadIdx.x;
    const int lane = tid & 63, w = tid >> 6, c = lane & 15, g = lane >> 4;
    const int id = blockIdx.x;
    const int p_pair = id & 127;
    const int t0 = (id >> 7) * 64;
    const int bn = p_pair >> 2, part = p_pair & 3;
    const int b = bn >> 4, n = bn & 15;
    const int s_start = part * 512;

    const unsigned short* qp = qu + (size_t)(b * 1024 + t0 + 16 * w + c) * 1024 + n * 64 + g * 8;
    bf16x8 qf0 = *(const bf16x8*)qp;
    bf16x8 qf1 = *(const bf16x8*)(qp + 32);
    const _Float16* qvp = qv + (size_t)(b * 1024 + t0 + 16 * w + c) * 1024 + n * 64 + g * 8;
    half8 av0 = *(const half8*)qvp;
    half8 av1 = *(const half8*)(qvp + 32);
    int r2 = t0 + 16 * w + c + 1; if (r2 > 1023) r2 = 1023;   // row t=1023 never uses wrap
    const _Float16* qvp2 = qv + (size_t)(b * 1024 + r2) * 1024 + n * 64 + g * 8;
    half8 aw0 = *(const half8*)qvp2;
    half8 aw1 = *(const half8*)(qvp2 + 32);

    const _Float16* rbase = rb + (size_t)n * 2049 * 64;

    f32x4 o[4] = {};
    float l_i[4] = {0.f, 0.f, 0.f, 0.f};

    const int sr = tid >> 2, scc = (tid & 3) * 16;
    const unsigned short* kstage = kg + (size_t)(b * 2048 + s_start + sr) * 1024 + n * 64 + scc;
    const unsigned short* vstage = vt + ((size_t)bn * 64 + sr) * 2048 + s_start + scc;

    auto bd_tile = [&](int Dbase, int nj) {
        for (int j = 0; j < nj; j++) {
            int Dl = Dbase + 16 * j + c;
            int Dmin = Dbase + 16 * j;
            int mm;
            if (Dl <= 1026) { mm = Dl + 1023; if (mm > 2048) mm = 2048; }
            else mm = Dl - 1027;
            const _Float16* rp = rbase + (size_t)mm * 64 + g * 8;
            half8 rb0 = *(const half8*)rp;
            half8 rb1 = *(const half8*)(rp + 32);
            f32x4 z;
            if (Dmin + 15 <= 1026) {
                f32x4 zm = {};
                zm = __builtin_amdgcn_mfma_f32_16x16x32_f16(av0, rb0, zm, 0, 0, 0);
                zm = __builtin_amdgcn_mfma_f32_16x16x32_f16(av1, rb1, zm, 0, 0, 0);
                z = zm;
            } else if (Dmin >= 1027) {
                f32x4 zw = {};
                zw = __builtin_amdgcn_mfma_f32_16x16x32_f16(aw0, rb0, zw, 0, 0, 0);
                zw = __builtin_amdgcn_mfma_f32_16x16x32_f16(aw1, rb1, zw, 0, 0, 0);
                z = zw;
            } else {
                f32x4 zm = {}, zw = {};
                zm = __builtin_amdgcn_mfma_f32_16x16x32_f16(av0, rb0, zm, 0, 0, 0);
                zm = __builtin_amdgcn_mfma_f32_16x16x32_f16(av1, rb1, zm, 0, 0, 0);
                zw = __builtin_amdgcn_mfma_f32_16x16x32_f16(aw0, rb0, zw, 0, 0, 0);
                zw = __builtin_amdgcn_mfma_f32_16x16x32_f16(aw1, rb1, zw, 0, 0, 0);
                z = (Dl >= 1027) ? zw : zm;
            }
            if (Dl == 1026) { z[0] = 0.f; z[1] = 0.f; z[2] = 0.f; z[3] = 0.f; }
            half4 hv;
            #pragma unroll
            for (int rg = 0; rg < 4; rg++) hv[rg] = (_Float16)z[rg];
            *(half4*)&BDT[Dl & 127][16 * w + 4 * g] = hv;     // wave-private cols
        }
    };

    for (int kk = 0; kk < 8; kk++) {
        const int s0 = s_start + kk * 64;
        const int diff0 = s0 - t0;

        *(uint4*)&Ks[sr][scc]     = *(const uint4*)(kstage + (size_t)(kk * 64) * 1024);
        *(uint4*)&Ks[sr][scc + 8] = *(const uint4*)(kstage + (size_t)(kk * 64) * 1024 + 8);
        *(uint4*)&Vs[sr][scc]     = *(const uint4*)(vstage + kk * 64);
        *(uint4*)&Vs[sr][scc + 8] = *(const uint4*)(vstage + kk * 64 + 8);

        if (kk == 0) bd_tile(diff0 - 63, 8);
        else         bd_tile(diff0 + 1, 4);

        __syncthreads();

        #pragma unroll
        for (int j = 0; j < 4; j++) {
            bf16x8 kf0 = *(const bf16x8*)&Ks[16 * j + c][g * 8];
            bf16x8 kf1 = *(const bf16x8*)&Ks[16 * j + c][32 + g * 8];
            f32x4 sa = {};
            sa = __builtin_amdgcn_mfma_f32_16x16x32_bf16(qf0, kf0, sa, 0, 0, 0);
            sa = __builtin_amdgcn_mfma_f32_16x16x32_bf16(qf1, kf1, sa, 0, 0, 0);
            #pragma unroll
            for (int rg = 0; rg < 4; rg++) {
                int tt = 16 * w + 4 * g + rg;
                int D = diff0 + 16 * j + c - tt;
                float bdt = (float)BDT[D & 127][tt];
                float p = exp2f(fmaf(sa[rg], C_SCALE, bdt));
                l_i[rg] += p;
                Ps[tt][16 * j + c] = bf16_rne(p);
            }
        }

        bf16x8 pf0 = *(const bf16x8*)&Ps[16 * w + c][g * 8];
        bf16x8 pf1 = *(const bf16x8*)&Ps[16 * w + c][32 + g * 8];
        #pragma unroll
        for (int j = 0; j < 4; j++) {
            bf16x8 vf0 = *(const bf16x8*)&Vs[16 * j + c][g * 8];
            bf16x8 vf1 = *(const bf16x8*)&Vs[16 * j + c][32 + g * 8];
            o[j] = __builtin_amdgcn_mfma_f32_16x16x32_bf16(pf0, vf0, o[j], 0, 0, 0);
            o[j] = __builtin_amdgcn_mfma_f32_16x16x32_bf16(pf1, vf1, o[j], 0, 0, 0);
        }
        __syncthreads();
    }

    #pragma unroll
    for (int rg = 0; rg < 4; rg++) {
        float s2 = l_i[rg];
        #pragma unroll
        for (int off = 1; off < 16; off <<= 1)
            s2 += __shfl_xor(s2, off, 16);
        int t = t0 + 16 * w + 4 * g + rg;
        size_t rowb = ((size_t)part * 32 + bn) * 1024 + t;
        if (c == 0) pl[rowb] = s2;
        #pragma unroll
        for (int j = 0; j < 4; j++)
            po[rowb * 64 + 16 * j + c] = o[j][rg];
    }
}

// ---------------------------------------------------------------------------
// Combine partitions: attn = (sum_p o_p) / (sum_p l_p), fp16 [B,T,NH]
// ---------------------------------------------------------------------------
__global__ __launch_bounds__(256) void combine_kernel(
    const float* __restrict__ po, const float* __restrict__ pl,
    _Float16* __restrict__ attn)
{
    int f = blockIdx.x * 256 + threadIdx.x;
    int h = f & 63, t = (f >> 6) & 1023, bn = f >> 16;
    float os = 0.f, ls = 0.f;
    #pragma unroll
    for (int p = 0; p < 4; p++) {
        size_t rowb = ((size_t)p * 32 + bn) * 1024 + t;
        os += po[rowb * 64 + h];
        ls += pl[rowb];
    }
    int b = bn >> 4, n = bn & 15;
    attn[((size_t)b * 1024 + t) * 1024 + n * 64 + h] = (_Float16)(os / ls);
}

// ---------------------------------------------------------------------------
// Output GEMM: out[bt,f] = sum_nh attn[bt,nh]*Woutt[f,nh] + b_out[f]
// Same lds-dma structure as proj2 (single B).
// ---------------------------------------------------------------------------
__global__ __launch_bounds__(256) void out2_kernel(
    const _Float16* __restrict__ A, const _Float16* __restrict__ Bt,
    const float* __restrict__ bias, float* __restrict__ out)
{
    alignas(16) __shared__ _Float16 As[4096];
    alignas(16) __shared__ _Float16 Bs[4096];
    const int tid = threadIdx.x;
    const int lane = tid & 63, w = tid >> 6, c = lane & 15, g = lane >> 4;
    const int row0 = blockIdx.x * 64, col0 = blockIdx.y * 64;
    const int srow = 16 * w + (lane >> 3);
    const int phys = lane & 7;
    f32x4 acc[4] = {};

    for (int k0 = 0; k0 < 1024; k0 += 64) {
        #pragma unroll
        for (int q = 0; q < 2; q++) {
            int row = srow + 8 * q;
            int log = phys ^ (row & 7);
            lds_dma16(A  + (size_t)(row0 + row) * 1024 + k0 + log * 8, &As[(16 * w + 8 * q) * 64]);
            lds_dma16(Bt + (size_t)(col0 + row) * 1024 + k0 + log * 8, &Bs[(16 * w + 8 * q) * 64]);
        }
        __syncthreads();
        #pragma unroll
        for (int s = 0; s < 2; s++) {
            const int pc = ((4 * s + g) ^ (c & 7)) * 8;
            half8 af = *(const half8*)&As[(16 * w + c) * 64 + pc];
            #pragma unroll
            for (int j = 0; j < 4; j++) {
                half8 bf = *(const half8*)&Bs[(16 * j + c) * 64 + pc];
                acc[j] = __builtin_amdgcn_mfma_f32_16x16x32_f16(af, bf, acc[j], 0, 0, 0);
            }
        }
        __syncthreads();
    }
    #pragma unroll
    for (int j = 0; j < 4; j++)
        #pragma unroll
        for (int rg = 0; rg < 4; rg++) {
            int r_g = row0 + 16 * w + g * 4 + rg, cg = col0 + 16 * j + c;
            out[(size_t)r_g * 1024 + cg] = acc[j][rg] + bias[cg];
        }
}

extern "C" void kernel_launch(void* const* d_in, const int* in_sizes, int n_in,
                              void* d_out, int out_size, void* d_ws, size_t ws_size,
                              hipStream_t stream)
{
    const float* x    = (const float*)d_in[0];
    const float* rel  = (const float*)d_in[1];
    const float* mem  = (const float*)d_in[2];
    const float* Wq   = (const float*)d_in[3];
    const float* Wk   = (const float*)d_in[4];
    const float* Wv   = (const float*)d_in[5];
    const float* Wr   = (const float*)d_in[6];
    const float* ub   = (const float*)d_in[7];
    const float* vb   = (const float*)d_in[8];
    const float* Wout = (const float*)d_in[9];
    const float* bout = (const float*)d_in[10];
    float* out = (float*)d_out;

    char* ws = (char*)d_ws;
    unsigned short* qu    = (unsigned short*)(ws);                   // 4 MB   bf16 [B,T,NH]
    _Float16*       qv    = (_Float16*)(ws + (4ull << 20));          // 4 MB   fp16 [B,T,NH] (*C_SCALE)
    unsigned short* kb    = (unsigned short*)(ws + (8ull << 20));    // 8 MB   bf16 [B,S,NH]
    unsigned short* vtb   = (unsigned short*)(ws + (16ull << 20));   // 8 MB   bf16 [B,N,H,S]
    _Float16*       rb    = (_Float16*)(ws + (24ull << 20));         // 4.2 MB fp16 [N,M,H]
    _Float16*       attn  = (_Float16*)(ws + (29ull << 20));         // 4 MB   fp16 [B,T,NH]
    float*          po    = (float*)(ws + (33ull << 20));            // 33.6MB fp32 [4,BN,T,H]
    float*          pl    = (float*)(ws + (68ull << 20));            // 0.5 MB fp32 [4,BN,T]
    _Float16*       x16   = (_Float16*)(ws + (69ull << 20));         // 4 MB
    _Float16*       mem16 = (_Float16*)(ws + (73ull << 20));         // 8 MB
    _Float16*       rel16 = (_Float16*)(ws + (81ull << 20));         // 4.2 MB
    _Float16*       Wqt   = (_Float16*)(ws + (86ull << 20));         // 2 MB each
    _Float16*       Wkt   = (_Float16*)(ws + (88ull << 20));
    _Float16*       Wvt   = (_Float16*)(ws + (90ull << 20));
    _Float16*       Wrt   = (_Float16*)(ws + (92ull << 20));
    _Float16*       Woutt = (_Float16*)(ws + (94ull << 20));

    convert_kernel<<<dim3(4097), 256, 0, stream>>>(x, mem, rel, x16, mem16, rel16);
    transpose_kernel<<<dim3(16, 16, 5), 256, 0, stream>>>(
        Wq, Wk, Wv, Wr, Wout, Wqt, Wkt, Wvt, Wrt, Woutt);
    proj2_kernel<<<dim3(129, 16), 256, 0, stream>>>(
        x16, mem16, rel16, Wqt, Wkt, Wvt, Wrt, ub, vb, qu, qv, kb, vtb, rb);
    flash_kernel<<<dim3(2048), 256, 0, stream>>>(qu, qv, kb, vtb, rb, po, pl);
    combine_kernel<<<dim3(8192), 256, 0, stream>>>(po, pl, attn);
    out2_kernel<<<dim3(32, 16), 256, 0, stream>>>(attn, Woutt, bout, out);
}

// Round 5
// 280.255 us; speedup vs baseline: 1.6792x; 1.1418x over previous
//
#include <hip/hip_runtime.h>
#include <cmath>

#define C_SCALE 0.18033688011112042f   // 0.125 * log2(e)

typedef __attribute__((ext_vector_type(8))) short bf16x8;
typedef __attribute__((ext_vector_type(8))) _Float16 half8;
typedef __attribute__((ext_vector_type(4))) _Float16 half4;
typedef __attribute__((ext_vector_type(4))) float f32x4;
typedef __attribute__((ext_vector_type(4))) unsigned short us4;

__device__ inline unsigned short bf16_rne(float f) {
    unsigned u = __builtin_bit_cast(unsigned, f);
    u += 0x7fff + ((u >> 16) & 1);
    return (unsigned short)(u >> 16);
}

__device__ inline void lds_dma16(const _Float16* g, _Float16* l) {
    __builtin_amdgcn_global_load_lds(
        (__attribute__((address_space(1))) void*)(void*)g,
        (__attribute__((address_space(3))) void*)(void*)l, 16, 0, 0);
}

// ---------------------------------------------------------------------------
// Fused prep: bx<1280 -> transpose W matrices fp32->fp16 (Wt[col][k]);
// bx>=1280 -> fp32->fp16 convert of x/mem/rel.
// ---------------------------------------------------------------------------
__global__ __launch_bounds__(256) void prep_kernel(
    const float* __restrict__ x, const float* __restrict__ mem,
    const float* __restrict__ rel,
    const float* __restrict__ s0, const float* __restrict__ s1,
    const float* __restrict__ s2, const float* __restrict__ s3,
    const float* __restrict__ s4,
    _Float16* __restrict__ x16, _Float16* __restrict__ mem16,
    _Float16* __restrict__ rel16,
    _Float16* __restrict__ d0, _Float16* __restrict__ d1,
    _Float16* __restrict__ d2, _Float16* __restrict__ d3,
    _Float16* __restrict__ d4)
{
    const int bx = blockIdx.x, tid = threadIdx.x;
    if (bx < 1280) {
        __shared__ _Float16 T[64][72];
        const int z = bx >> 8, rem = bx & 255;
        const float* src = z == 0 ? s0 : z == 1 ? s1 : z == 2 ? s2 : z == 3 ? s3 : s4;
        _Float16*    dst = z == 0 ? d0 : z == 1 ? d1 : z == 2 ? d2 : z == 3 ? d3 : d4;
        const int r0 = (rem & 15) * 64, c0 = (rem >> 4) * 64;
        const int r = tid >> 4, c4 = (tid & 15) * 4;
        #pragma unroll
        for (int rr = 0; rr < 64; rr += 16) {
            float4 v = *(const float4*)(src + (size_t)(r0 + r + rr) * 1024 + c0 + c4);
            T[c4 + 0][r + rr] = (_Float16)v.x;
            T[c4 + 1][r + rr] = (_Float16)v.y;
            T[c4 + 2][r + rr] = (_Float16)v.z;
            T[c4 + 3][r + rr] = (_Float16)v.w;
        }
        __syncthreads();
        const int orow = tid >> 2, seg = (tid & 3) * 16;
        half8 h0 = *(const half8*)&T[orow][seg];
        half8 h1 = *(const half8*)&T[orow][seg + 8];
        *(half8*)(dst + (size_t)(c0 + orow) * 1024 + r0 + seg)     = h0;
        *(half8*)(dst + (size_t)(c0 + orow) * 1024 + r0 + seg + 8) = h1;
    } else {
        size_t i = ((size_t)(bx - 1280) * 256 + tid) * 8;
        if (i >= 8389632ull) return;
        const float* src; _Float16* dst; size_t off;
        if (i < 2097152ull)      { src = x;   dst = x16;   off = i; }
        else if (i < 6291456ull) { src = mem; dst = mem16; off = i - 2097152ull; }
        else                     { src = rel; dst = rel16; off = i - 6291456ull; }
        float4 a = *(const float4*)(src + off);
        float4 b = *(const float4*)(src + off + 4);
        half8 h;
        h[0]=(_Float16)a.x; h[1]=(_Float16)a.y; h[2]=(_Float16)a.z; h[3]=(_Float16)a.w;
        h[4]=(_Float16)b.x; h[5]=(_Float16)b.y; h[6]=(_Float16)b.z; h[7]=(_Float16)b.w;
        *(half8*)(dst + off) = h;
    }
}

// ---------------------------------------------------------------------------
// 128x128-tile projection GEMM (fp16, global_load_lds, XOR swizzle, BK=64).
// bx: [0,16) Q; [16,48) K; [48,80) V(transposed out); [80,97) R. grid.y=8.
// ---------------------------------------------------------------------------
__global__ __launch_bounds__(256) void proj3_kernel(
    const _Float16* __restrict__ x16, const _Float16* __restrict__ mem16,
    const _Float16* __restrict__ rel16,
    const _Float16* __restrict__ Wqt, const _Float16* __restrict__ Wkt,
    const _Float16* __restrict__ Wvt, const _Float16* __restrict__ Wrt,
    const float* __restrict__ ub, const float* __restrict__ vb,
    unsigned short* __restrict__ qu, _Float16* __restrict__ qv,
    unsigned short* __restrict__ kb, unsigned short* __restrict__ vtb,
    _Float16* __restrict__ rb)
{
    alignas(16) __shared__ _Float16 As[128 * 64];
    alignas(16) __shared__ _Float16 Bs[128 * 64];
    const int tid = threadIdx.x;
    const int lane = tid & 63, w = tid >> 6, c = lane & 15, g = lane >> 4;
    const int bx = blockIdx.x, col0 = blockIdx.y * 128;

    int mode, row0, rowmax;
    const _Float16 *Ap, *Bp;
    if (bx < 16)      { mode = 0; row0 = bx * 128;        rowmax = 2047; Ap = x16;   Bp = Wqt; }
    else if (bx < 48) { mode = 1; row0 = (bx - 16) * 128; rowmax = 4095; Ap = mem16; Bp = Wkt; }
    else if (bx < 80) { mode = 2; row0 = (bx - 48) * 128; rowmax = 4095; Ap = mem16; Bp = Wvt; }
    else              { mode = 3; row0 = (bx - 80) * 128; rowmax = 2048; Ap = rel16; Bp = Wrt; }

    const int qr = (w & 1) * 64, qc = (w >> 1) * 64;
    const int srow = lane >> 3, phys = lane & 7;
    f32x4 acc[4][4] = {};

    for (int k0 = 0; k0 < 1024; k0 += 64) {
        #pragma unroll
        for (int q = 0; q < 4; q++) {
            int row = 32 * w + 8 * q + srow;
            int log = phys ^ (row & 7);
            int ar = row0 + row; if (ar > rowmax) ar = rowmax;
            lds_dma16(Ap + (size_t)ar * 1024 + k0 + log * 8, &As[(32 * w + 8 * q) * 64]);
            lds_dma16(Bp + (size_t)(col0 + row) * 1024 + k0 + log * 8, &Bs[(32 * w + 8 * q) * 64]);
        }
        __syncthreads();
        #pragma unroll
        for (int s = 0; s < 2; s++) {
            half8 af[4], bf[4];
            #pragma unroll
            for (int i = 0; i < 4; i++) {
                int row = qr + 16 * i + c;
                af[i] = *(const half8*)&As[row * 64 + ((4 * s + g) ^ (row & 7)) * 8];
            }
            #pragma unroll
            for (int j = 0; j < 4; j++) {
                int row = qc + 16 * j + c;
                bf[j] = *(const half8*)&Bs[row * 64 + ((4 * s + g) ^ (row & 7)) * 8];
            }
            #pragma unroll
            for (int i = 0; i < 4; i++)
                #pragma unroll
                for (int j = 0; j < 4; j++)
                    acc[i][j] = __builtin_amdgcn_mfma_f32_16x16x32_f16(af[i], bf[j], acc[i][j], 0, 0, 0);
        }
        __syncthreads();
    }

    #pragma unroll
    for (int i = 0; i < 4; i++) {
        #pragma unroll
        for (int j = 0; j < 4; j++) {
            const int cg = col0 + qc + 16 * j + c;
            const int rbase = row0 + qr + 16 * i + 4 * g;
            if (mode == 0) {
                float u = ub[cg], v = vb[cg];
                #pragma unroll
                for (int rg = 0; rg < 4; rg++) {
                    size_t o = (size_t)(rbase + rg) * 1024 + cg;
                    qu[o] = bf16_rne(acc[i][j][rg] + u);
                    qv[o] = (_Float16)((acc[i][j][rg] + v) * C_SCALE);
                }
            } else if (mode == 1) {
                #pragma unroll
                for (int rg = 0; rg < 4; rg++)
                    kb[(size_t)(rbase + rg) * 1024 + cg] = bf16_rne(acc[i][j][rg]);
            } else if (mode == 2) {
                us4 pk;
                #pragma unroll
                for (int rg = 0; rg < 4; rg++) pk[rg] = bf16_rne(acc[i][j][rg]);
                int b = rbase >> 11, s = rbase & 2047;
                *(us4*)&vtb[((size_t)(b * 16 + (cg >> 6)) * 64 + (cg & 63)) * 2048 + s] = pk;
            } else {
                #pragma unroll
                for (int rg = 0; rg < 4; rg++) {
                    int r_g = rbase + rg;
                    if (r_g < 2049)
                        rb[((size_t)(cg >> 6) * 2049 + r_g) * 64 + (cg & 63)] = (_Float16)acc[i][j][rg];
                }
            }
        }
    }
}

// ---------------------------------------------------------------------------
// Flash attention, s-split x4, register-pipelined K/V/r prefetch across
// barriers, incremental circular BD window, unnormalized softmax.
// Outputs normalized o (fp16) + partition row-sum l (fp32).
// ---------------------------------------------------------------------------
__global__ __launch_bounds__(256) void flash_kernel(
    const unsigned short* __restrict__ qu, const _Float16* __restrict__ qv,
    const unsigned short* __restrict__ kg, const unsigned short* __restrict__ vt,
    const _Float16* __restrict__ rb, _Float16* __restrict__ po, float* __restrict__ pl)
{
    __shared__ unsigned short Ks[64][70];
    __shared__ unsigned short Vs[64][70];
    __shared__ unsigned short Ps[64][70];
    __shared__ _Float16 BDT[128][70];
    const int tid = threadIdx.x;
    const int lane = tid & 63, w = tid >> 6, c = lane & 15, g = lane >> 4;
    const int id = blockIdx.x;
    const int p_pair = id & 127;
    const int t0 = (id >> 7) * 64;
    const int bn = p_pair >> 2, part = p_pair & 3;
    const int b = bn >> 4, n = bn & 15;
    const int s_start = part * 512;

    const unsigned short* qp = qu + (size_t)(b * 1024 + t0 + 16 * w + c) * 1024 + n * 64 + g * 8;
    bf16x8 qf0 = *(const bf16x8*)qp;
    bf16x8 qf1 = *(const bf16x8*)(qp + 32);
    const _Float16* qvp = qv + (size_t)(b * 1024 + t0 + 16 * w + c) * 1024 + n * 64 + g * 8;
    half8 av0 = *(const half8*)qvp;
    half8 av1 = *(const half8*)(qvp + 32);
    int r2 = t0 + 16 * w + c + 1; if (r2 > 1023) r2 = 1023;
    const _Float16* qvp2 = qv + (size_t)(b * 1024 + r2) * 1024 + n * 64 + g * 8;
    half8 aw0 = *(const half8*)qvp2;
    half8 aw1 = *(const half8*)(qvp2 + 32);

    const _Float16* rbase = rb + (size_t)n * 2049 * 64;

    f32x4 o[4] = {};
    float l_i[4] = {0.f, 0.f, 0.f, 0.f};

    const int sr = tid >> 2, scc = (tid & 3) * 16;
    const unsigned short* kstage = kg + (size_t)(b * 2048 + s_start + sr) * 1024 + n * 64 + scc;
    const unsigned short* vstage = vt + ((size_t)bn * 64 + sr) * 2048 + s_start + scc;

    auto r_ptr = [&](int Dl) {
        int mm = (Dl <= 1026) ? (Dl + 1023 > 2048 ? 2048 : Dl + 1023) : Dl - 1027;
        return rbase + (size_t)mm * 64 + g * 8;
    };
    auto bd_one = [&](int Dbase, int j, half8 r0, half8 r1) {
        int Dl = Dbase + 16 * j + c;
        int Dmin = Dbase + 16 * j;
        f32x4 z;
        if (Dmin + 15 <= 1026) {
            f32x4 zm = {};
            zm = __builtin_amdgcn_mfma_f32_16x16x32_f16(av0, r0, zm, 0, 0, 0);
            zm = __builtin_amdgcn_mfma_f32_16x16x32_f16(av1, r1, zm, 0, 0, 0);
            z = zm;
        } else if (Dmin >= 1027) {
            f32x4 zw = {};
            zw = __builtin_amdgcn_mfma_f32_16x16x32_f16(aw0, r0, zw, 0, 0, 0);
            zw = __builtin_amdgcn_mfma_f32_16x16x32_f16(aw1, r1, zw, 0, 0, 0);
            z = zw;
        } else {
            f32x4 zm = {}, zw = {};
            zm = __builtin_amdgcn_mfma_f32_16x16x32_f16(av0, r0, zm, 0, 0, 0);
            zm = __builtin_amdgcn_mfma_f32_16x16x32_f16(av1, r1, zm, 0, 0, 0);
            zw = __builtin_amdgcn_mfma_f32_16x16x32_f16(aw0, r0, zw, 0, 0, 0);
            zw = __builtin_amdgcn_mfma_f32_16x16x32_f16(aw1, r1, zw, 0, 0, 0);
            z = (Dl >= 1027) ? zw : zm;
        }
        if (Dl == 1026) { z[0] = 0.f; z[1] = 0.f; z[2] = 0.f; z[3] = 0.f; }
        half4 hv;
        #pragma unroll
        for (int rg = 0; rg < 4; rg++) hv[rg] = (_Float16)z[rg];
        *(half4*)&BDT[Dl & 127][16 * w + 4 * g] = hv;
    };

    // ---- preload tile 0: K/V regs, r regs (full 128-col window) ----
    const int d0 = s_start - t0;
    half8 rx[8], rr[8];
    #pragma unroll
    for (int j = 0; j < 4; j++) {
        const _Float16* rp = r_ptr(d0 - 63 + 16 * j + c);
        rx[2 * j] = *(const half8*)rp; rx[2 * j + 1] = *(const half8*)(rp + 32);
    }
    #pragma unroll
    for (int j = 0; j < 4; j++) {
        const _Float16* rp = r_ptr(d0 + 1 + 16 * j + c);
        rr[2 * j] = *(const half8*)rp; rr[2 * j + 1] = *(const half8*)(rp + 32);
    }
    uint4 k0r = *(const uint4*)(kstage);
    uint4 k1r = *(const uint4*)(kstage + 8);
    uint4 v0r = *(const uint4*)(vstage);
    uint4 v1r = *(const uint4*)(vstage + 8);

    for (int kk = 0; kk < 8; kk++) {
        const int diff0 = d0 + kk * 64;

        // VGPR -> LDS (loads long since returned); BD MFMAs on resident regs
        *(uint4*)&Ks[sr][scc]     = k0r;
        *(uint4*)&Ks[sr][scc + 8] = k1r;
        *(uint4*)&Vs[sr][scc]     = v0r;
        *(uint4*)&Vs[sr][scc + 8] = v1r;
        if (kk == 0) {
            #pragma unroll
            for (int j = 0; j < 4; j++) bd_one(d0 - 63, j, rx[2 * j], rx[2 * j + 1]);
        }
        #pragma unroll
        for (int j = 0; j < 4; j++) bd_one(diff0 + 1, j, rr[2 * j], rr[2 * j + 1]);

        __syncthreads();

        // ---- prefetch tile kk+1 into registers (overlaps softmax/PV) ----
        const int kn = kk < 7 ? kk + 1 : 7;
        k0r = *(const uint4*)(kstage + (size_t)(kn * 64) * 1024);
        k1r = *(const uint4*)(kstage + (size_t)(kn * 64) * 1024 + 8);
        v0r = *(const uint4*)(vstage + kn * 64);
        v1r = *(const uint4*)(vstage + kn * 64 + 8);
        const int Dn = diff0 + 65;
        #pragma unroll
        for (int j = 0; j < 4; j++) {
            const _Float16* rp = r_ptr(Dn + 16 * j + c);
            rr[2 * j] = *(const half8*)rp; rr[2 * j + 1] = *(const half8*)(rp + 32);
        }

        // ---- logits + unnormalized softmax ----
        #pragma unroll
        for (int j = 0; j < 4; j++) {
            bf16x8 kf0 = *(const bf16x8*)&Ks[16 * j + c][g * 8];
            bf16x8 kf1 = *(const bf16x8*)&Ks[16 * j + c][32 + g * 8];
            f32x4 sa = {};
            sa = __builtin_amdgcn_mfma_f32_16x16x32_bf16(qf0, kf0, sa, 0, 0, 0);
            sa = __builtin_amdgcn_mfma_f32_16x16x32_bf16(qf1, kf1, sa, 0, 0, 0);
            #pragma unroll
            for (int rg = 0; rg < 4; rg++) {
                int tt = 16 * w + 4 * g + rg;
                int D = diff0 + 16 * j + c - tt;
                float bdt = (float)BDT[D & 127][tt];
                float p = exp2f(fmaf(sa[rg], C_SCALE, bdt));
                l_i[rg] += p;
                Ps[tt][16 * j + c] = bf16_rne(p);
            }
        }

        bf16x8 pf0 = *(const bf16x8*)&Ps[16 * w + c][g * 8];
        bf16x8 pf1 = *(const bf16x8*)&Ps[16 * w + c][32 + g * 8];
        #pragma unroll
        for (int j = 0; j < 4; j++) {
            bf16x8 vf0 = *(const bf16x8*)&Vs[16 * j + c][g * 8];
            bf16x8 vf1 = *(const bf16x8*)&Vs[16 * j + c][32 + g * 8];
            o[j] = __builtin_amdgcn_mfma_f32_16x16x32_bf16(pf0, vf0, o[j], 0, 0, 0);
            o[j] = __builtin_amdgcn_mfma_f32_16x16x32_bf16(pf1, vf1, o[j], 0, 0, 0);
        }
        __syncthreads();
    }

    #pragma unroll
    for (int rg = 0; rg < 4; rg++) {
        float s2 = l_i[rg];
        #pragma unroll
        for (int off = 1; off < 16; off <<= 1)
            s2 += __shfl_xor(s2, off, 16);
        int t = t0 + 16 * w + 4 * g + rg;
        size_t rowb = ((size_t)part * 32 + bn) * 1024 + t;
        if (c == 0) pl[rowb] = s2;
        float inv = 1.f / s2;
        #pragma unroll
        for (int j = 0; j < 4; j++)
            po[rowb * 64 + 16 * j + c] = (_Float16)(o[j][rg] * inv);
    }
}

// ---------------------------------------------------------------------------
// Combine: attn = sum_p l_p * po_p / sum_p l_p
// ---------------------------------------------------------------------------
__global__ __launch_bounds__(256) void combine_kernel(
    const _Float16* __restrict__ po, const float* __restrict__ pl,
    _Float16* __restrict__ attn)
{
    int f = blockIdx.x * 256 + threadIdx.x;
    int h = f & 63, t = (f >> 6) & 1023, bn = f >> 16;
    float os = 0.f, ls = 0.f;
    #pragma unroll
    for (int p = 0; p < 4; p++) {
        size_t rowb = ((size_t)p * 32 + bn) * 1024 + t;
        float lp = pl[rowb];
        os += lp * (float)po[rowb * 64 + h];
        ls += lp;
    }
    int b = bn >> 4, n = bn & 15;
    attn[((size_t)b * 1024 + t) * 1024 + n * 64 + h] = (_Float16)(os / ls);
}

// ---------------------------------------------------------------------------
// Output GEMM: out[bt,f] = sum_nh attn[bt,nh]*Woutt[f,nh] + b_out[f]
// ---------------------------------------------------------------------------
__global__ __launch_bounds__(256) void out2_kernel(
    const _Float16* __restrict__ A, const _Float16* __restrict__ Bt,
    const float* __restrict__ bias, float* __restrict__ out)
{
    alignas(16) __shared__ _Float16 As[4096];
    alignas(16) __shared__ _Float16 Bs[4096];
    const int tid = threadIdx.x;
    const int lane = tid & 63, w = tid >> 6, c = lane & 15, g = lane >> 4;
    const int row0 = blockIdx.x * 64, col0 = blockIdx.y * 64;
    const int srow = 16 * w + (lane >> 3);
    const int phys = lane & 7;
    f32x4 acc[4] = {};

    for (int k0 = 0; k0 < 1024; k0 += 64) {
        #pragma unroll
        for (int q = 0; q < 2; q++) {
            int row = srow + 8 * q;
            int log = phys ^ (row & 7);
            lds_dma16(A  + (size_t)(row0 + row) * 1024 + k0 + log * 8, &As[(16 * w + 8 * q) * 64]);
            lds_dma16(Bt + (size_t)(col0 + row) * 1024 + k0 + log * 8, &Bs[(16 * w + 8 * q) * 64]);
        }
        __syncthreads();
        #pragma unroll
        for (int s = 0; s < 2; s++) {
            const int pc = ((4 * s + g) ^ (c & 7)) * 8;
            half8 af = *(const half8*)&As[(16 * w + c) * 64 + pc];
            #pragma unroll
            for (int j = 0; j < 4; j++) {
                half8 bf = *(const half8*)&Bs[(16 * j + c) * 64 + pc];
                acc[j] = __builtin_amdgcn_mfma_f32_16x16x32_f16(af, bf, acc[j], 0, 0, 0);
            }
        }
        __syncthreads();
    }
    #pragma unroll
    for (int j = 0; j < 4; j++)
        #pragma unroll
        for (int rg = 0; rg < 4; rg++) {
            int r_g = row0 + 16 * w + g * 4 + rg, cg = col0 + 16 * j + c;
            out[(size_t)r_g * 1024 + cg] = acc[j][rg] + bias[cg];
        }
}

extern "C" void kernel_launch(void* const* d_in, const int* in_sizes, int n_in,
                              void* d_out, int out_size, void* d_ws, size_t ws_size,
                              hipStream_t stream)
{
    const float* x    = (const float*)d_in[0];
    const float* rel  = (const float*)d_in[1];
    const float* mem  = (const float*)d_in[2];
    const float* Wq   = (const float*)d_in[3];
    const float* Wk   = (const float*)d_in[4];
    const float* Wv   = (const float*)d_in[5];
    const float* Wr   = (const float*)d_in[6];
    const float* ub   = (const float*)d_in[7];
    const float* vb   = (const float*)d_in[8];
    const float* Wout = (const float*)d_in[9];
    const float* bout = (const float*)d_in[10];
    float* out = (float*)d_out;

    char* ws = (char*)d_ws;
    unsigned short* qu    = (unsigned short*)(ws);                   // 4 MB   bf16 [B,T,NH]
    _Float16*       qv    = (_Float16*)(ws + (4ull << 20));          // 4 MB   fp16 [B,T,NH] (*C_SCALE)
    unsigned short* kb    = (unsigned short*)(ws + (8ull << 20));    // 8 MB   bf16 [B,S,NH]
    unsigned short* vtb   = (unsigned short*)(ws + (16ull << 20));   // 8 MB   bf16 [B,N,H,S]
    _Float16*       rb    = (_Float16*)(ws + (24ull << 20));         // 4.2 MB fp16 [N,M,H]
    _Float16*       attn  = (_Float16*)(ws + (29ull << 20));         // 4 MB   fp16 [B,T,NH]
    _Float16*       po    = (_Float16*)(ws + (33ull << 20));         // 16.8MB fp16 [4,BN,T,H]
    float*          pl    = (float*)(ws + (50ull << 20));            // 0.5 MB fp32 [4,BN,T]
    _Float16*       x16   = (_Float16*)(ws + (51ull << 20));         // 4 MB
    _Float16*       mem16 = (_Float16*)(ws + (55ull << 20));         // 8 MB
    _Float16*       rel16 = (_Float16*)(ws + (63ull << 20));         // 4.2 MB
    _Float16*       Wqt   = (_Float16*)(ws + (68ull << 20));         // 2 MB each
    _Float16*       Wkt   = (_Float16*)(ws + (70ull << 20));
    _Float16*       Wvt   = (_Float16*)(ws + (72ull << 20));
    _Float16*       Wrt   = (_Float16*)(ws + (74ull << 20));
    _Float16*       Woutt = (_Float16*)(ws + (76ull << 20));

    prep_kernel<<<dim3(5377), 256, 0, stream>>>(
        x, mem, rel, Wq, Wk, Wv, Wr, Wout,
        x16, mem16, rel16, Wqt, Wkt, Wvt, Wrt, Woutt);
    proj3_kernel<<<dim3(97, 8), 256, 0, stream>>>(
        x16, mem16, rel16, Wqt, Wkt, Wvt, Wrt, ub, vb, qu, qv, kb, vtb, rb);
    flash_kernel<<<dim3(2048), 256, 0, stream>>>(qu, qv, kb, vtb, rb, po, pl);
    combine_kernel<<<dim3(8192), 256, 0, stream>>>(po, pl, attn);
    out2_kernel<<<dim3(32, 16), 256, 0, stream>>>(attn, Woutt, bout, out);
}